// Round 1
// baseline (4807.430 us; speedup 1.0000x reference)
//
#include <hip/hip_runtime.h>

#define NN 16384
#define PERG 512
#define NGR 32
#define NE 262144
#define GCAP 16384

// ---------- helpers ----------
__device__ __forceinline__ unsigned encf(float f){
  unsigned u = __float_as_uint(f);
  return (u & 0x80000000u) ? ~u : (u | 0x80000000u);
}
__device__ __forceinline__ float decf(unsigned e){
  unsigned u = (e & 0x80000000u) ? (e ^ 0x80000000u) : ~e;
  return __uint_as_float(u);
}

// ---------- init ----------
__global__ void k_init_edges(const int* __restrict__ ei, int* __restrict__ src,
                             int* __restrict__ dst, int* __restrict__ em){
  int e = blockIdx.x*256 + threadIdx.x;
  if (e < NE){ src[e]=ei[e]; dst[e]=ei[NE+e]; em[e]=1; }
}
__global__ void k_init_nodes(int* __restrict__ valid){
  int i = blockIdx.x*256 + threadIdx.x;
  if (i < NN) valid[i]=1;
}

// ---------- dense matmul C[M,N] = A[M,K] @ W[K,N], f32 ----------
__global__ __launch_bounds__(256) void k_mm(const float* __restrict__ A, const float* __restrict__ W,
                                            float* __restrict__ C, int M, int K, int N){
  __shared__ float As[8][128];
  __shared__ float Ws[8][128];
  int col0 = blockIdx.x*128, row0 = blockIdx.y*128;
  int t = threadIdx.x, tx = t & 15, ty = t >> 4;
  float acc[8][8];
#pragma unroll
  for (int i=0;i<8;i++)
#pragma unroll
    for (int j=0;j<8;j++) acc[i][j]=0.f;
  for (int k0=0; k0<K; k0+=8){
#pragma unroll
    for (int i=0;i<4;i++){
      int idx = t*4+i; int m = idx>>3, kk = idx&7;
      As[kk][m] = (k0+kk<K) ? A[(size_t)(row0+m)*K + (k0+kk)] : 0.f;
    }
#pragma unroll
    for (int i=0;i<4;i++){
      int idx = t*4+i; int kk = idx>>7, nn = idx&127;
      Ws[kk][nn] = (k0+kk<K && col0+nn<N) ? W[(size_t)(k0+kk)*N + (col0+nn)] : 0.f;
    }
    __syncthreads();
#pragma unroll
    for (int kk=0;kk<8;kk++){
      float a[8], b[8];
#pragma unroll
      for (int i=0;i<4;i++){
        a[i]   = As[kk][ty*4+i];  a[4+i] = As[kk][64+ty*4+i];
        b[i]   = Ws[kk][tx*4+i];  b[4+i] = Ws[kk][64+tx*4+i];
      }
#pragma unroll
      for (int i=0;i<8;i++)
#pragma unroll
        for (int j=0;j<8;j++) acc[i][j] += a[i]*b[j];
    }
    __syncthreads();
  }
#pragma unroll
  for (int i=0;i<8;i++){
    int r = row0 + ((i<4)? ty*4+i : 64+ty*4+(i-4));
#pragma unroll
    for (int j=0;j<8;j++){
      int cc = col0 + ((j<4)? tx*4+j : 64+tx*4+(j-4));
      if (cc<N) C[(size_t)r*N+cc] = acc[i][j];
    }
  }
}

// ---------- degree / CSR ----------
__global__ void k_count(const int* __restrict__ src, const int* __restrict__ dst,
                        const int* __restrict__ em, int* __restrict__ cnt, int* __restrict__ hs){
  int e = blockIdx.x*256 + threadIdx.x;
  if (e<NE && em[e]){
    atomicAdd(&cnt[dst[e]], 1);
    if (src[e]==dst[e]) hs[dst[e]] = 1;
  }
}
__global__ __launch_bounds__(1024) void k_scan(const int* __restrict__ cnt, int* __restrict__ rowp,
                                               int* __restrict__ cursor){
  __shared__ int part[1024];
  int t = threadIdx.x;
  int base = t*16;
  int loc[16];
  int s = 0;
#pragma unroll
  for (int i=0;i<16;i++){ loc[i]=s; s += cnt[base+i]; }
  part[t] = s;
  __syncthreads();
  for (int off=1; off<1024; off<<=1){
    int v = (t>=off) ? part[t-off] : 0;
    __syncthreads();
    part[t] += v;
    __syncthreads();
  }
  int excl = (t==0) ? 0 : part[t-1];
#pragma unroll
  for (int i=0;i<16;i++){ int v = excl + loc[i]; rowp[base+i]=v; cursor[base+i]=v; }
  if (t==1023){ rowp[NN]=part[1023]; cursor[NN]=part[1023]; }
}
__global__ void k_fill(const int* __restrict__ dst, const int* __restrict__ em,
                       int* __restrict__ cursor, int* __restrict__ elist){
  int e = blockIdx.x*256 + threadIdx.x;
  if (e<NE && em[e]) elist[atomicAdd(&cursor[dst[e]],1)] = e;
}
__global__ void k_nodeprep(const int* __restrict__ cnt, const int* __restrict__ hs,
                           float* __restrict__ dinv, float* __restrict__ selfco){
  int i = blockIdx.x*256 + threadIdx.x;
  if (i<NN){
    float deg = (float)cnt[i] + (hs[i] ? 0.f : 1.f);
    dinv[i]   = rsqrtf(deg);
    selfco[i] = hs[i] ? 0.f : (1.f/deg);
  }
}

// ---------- GCN aggregation: y = agg + selfco*h + b (wave per node) ----------
template<int FO>
__global__ __launch_bounds__(256) void k_agg(const float* __restrict__ h, const int* __restrict__ rowp,
    const int* __restrict__ elist, const int* __restrict__ src, const float* __restrict__ dinv,
    const float* __restrict__ selfco, const float* __restrict__ bias, float* __restrict__ y){
  constexpr int Q = (FO+63)/64;
  int lane = threadIdx.x & 63;
  int i = blockIdx.x*4 + (threadIdx.x>>6);
  float acc[Q];
#pragma unroll
  for (int q=0;q<Q;q++) acc[q]=0.f;
  int s0 = rowp[i], s1 = rowp[i+1];
  float di = dinv[i];
  for (int p=s0; p<s1; p++){
    int e = elist[p]; int s = src[e];
    float nr = di * dinv[s];
    const float* hrow = h + (size_t)s*FO;
#pragma unroll
    for (int q=0;q<Q;q++){ int c=lane+q*64; if (c<FO) acc[q] += nr*hrow[c]; }
  }
  float sc = selfco[i];
  const float* hi = h + (size_t)i*FO;
  float* yi = y + (size_t)i*FO;
#pragma unroll
  for (int q=0;q<Q;q++){ int c=lane+q*64; if (c<FO) yi[c] = acc[q] + sc*hi[c] + bias[c]; }
}

// ---------- pool: per-node score partials ----------
template<int FO>
__global__ __launch_bounds__(256) void k_ab(const float* __restrict__ y, const float* __restrict__ Pw,
                                            float* __restrict__ aval, float* __restrict__ bval){
  constexpr int Q = (FO+63)/64;
  int lane = threadIdx.x & 63;
  int i = blockIdx.x*4 + (threadIdx.x>>6);
  const float* yi = y + (size_t)i*FO;
  float sa=0.f, sb=0.f;
#pragma unroll
  for (int q=0;q<Q;q++){ int c=lane+q*64; if (c<FO){ float v=yi[c]; sa += v*Pw[c]; sb += v*Pw[FO+c]; } }
  for (int o=32;o;o>>=1){ sa += __shfl_xor(sa,o); sb += __shfl_xor(sb,o); }
  if (lane==0){ aval[i]=sa; bval[i]=sb; }
}
__global__ void k_raw(const int* __restrict__ src, const int* __restrict__ dst, const int* __restrict__ em,
                      const float* __restrict__ aval, const float* __restrict__ bval,
                      const float* __restrict__ Pb, float* __restrict__ sc, unsigned* __restrict__ mx){
  int e = blockIdx.x*256 + threadIdx.x;
  if (e<NE && em[e]){
    float r = aval[src[e]] + bval[dst[e]] + Pb[0];
    sc[e] = r;
    atomicMax(&mx[dst[e]], encf(r));
  }
}
__global__ void k_ex(const int* __restrict__ dst, const int* __restrict__ em, float* __restrict__ sc,
                     const unsigned* __restrict__ mx, float* __restrict__ den){
  int e = blockIdx.x*256 + threadIdx.x;
  if (e<NE && em[e]){
    float ex = expf(sc[e] - decf(mx[dst[e]]));
    sc[e] = ex;
    atomicAdd(&den[dst[e]], ex);
  }
}
__global__ void k_score(const int* __restrict__ dst, const int* __restrict__ em,
                        float* __restrict__ sc, const float* __restrict__ den){
  int e = blockIdx.x*256 + threadIdx.x;
  if (e<NE && em[e]) sc[e] = sc[e]/fmaxf(den[dst[e]],1e-16f) + 0.1f;
}

// ---------- pool: per-node init ----------
__global__ void k_poolinit(int* __restrict__ cluster, float* __restrict__ nscore, int* __restrict__ partner){
  int i = blockIdx.x*256 + threadIdx.x;
  if (i<NN){ cluster[i]=i; nscore[i]=1.f; partner[i]=-1; }
}

// ---------- pool: build per-graph edge lists ----------
__global__ void k_build(const int* __restrict__ src, const int* __restrict__ dst, const int* __restrict__ em,
                        const float* __restrict__ sc, int* __restrict__ gcount,
                        int* __restrict__ gpk, unsigned* __restrict__ gsb, int* __restrict__ geid){
  int e = blockIdx.x*256 + threadIdx.x;
  if (e<NE && em[e]){
    int s = src[e], d = dst[e];
    int g = s >> 9;
    int slot = atomicAdd(&gcount[g],1);
    if (slot < GCAP){
      int b = g*GCAP + slot;
      gpk[b]  = ((s&511)<<9) | (d&511);
      gsb[b]  = __float_as_uint(sc[e]);   // score > 0 -> bits are order-preserving
      geid[b] = e;
    }
  }
}

// ---------- pool: greedy matching == iterative lexicographic local-max ----------
__global__ __launch_bounds__(256) void k_match(const int* __restrict__ gcount, const int* __restrict__ gpk,
    const unsigned* __restrict__ gsb, const int* __restrict__ geid,
    int* __restrict__ cluster, float* __restrict__ nscore, int* __restrict__ partner, int* __restrict__ valid){
  int g = blockIdx.x;
  __shared__ unsigned char marked[PERG];
  __shared__ unsigned best_s[PERG];
  __shared__ unsigned best_e[PERG];
  __shared__ int flag;
  int t = threadIdx.x;
  for (int i=t;i<PERG;i+=256) marked[i] = valid[g*PERG+i] ? 0 : 1;
  int nE = min(gcount[g], GCAP);
  int base = g*GCAP;
  for (int round=0; round<1024; ++round){
    for (int i=t;i<PERG;i+=256){ best_s[i]=0u; best_e[i]=0xFFFFFFFFu; }
    if (t==0) flag = 0;
    __syncthreads();
    for (int k=t;k<nE;k+=256){
      int pk = gpk[base+k]; int ls = pk>>9, ld = pk&511;
      if (marked[ls] | marked[ld]) continue;
      flag = 1;
      unsigned sb = gsb[base+k];
      atomicMax(&best_s[ls], sb);
      if (ld != ls) atomicMax(&best_s[ld], sb);
    }
    __syncthreads();
    if (!flag) break;
    for (int k=t;k<nE;k+=256){
      int pk = gpk[base+k]; int ls = pk>>9, ld = pk&511;
      if (marked[ls] | marked[ld]) continue;
      unsigned sb = gsb[base+k];
      unsigned eid = (unsigned)geid[base+k];
      if (sb == best_s[ls]) atomicMin(&best_e[ls], eid);
      if (sb == best_s[ld]) atomicMin(&best_e[ld], eid);
    }
    __syncthreads();
    for (int k=t;k<nE;k+=256){
      int pk = gpk[base+k]; int ls = pk>>9, ld = pk&511;
      if (marked[ls] | marked[ld]) continue;
      unsigned sb = gsb[base+k];
      unsigned eid = (unsigned)geid[base+k];
      if (sb==best_s[ls] && best_e[ls]==eid && sb==best_s[ld] && best_e[ld]==eid){
        int gs = g*PERG+ls, gd = g*PERG+ld;
        int rep = min(gs,gd), oth = max(gs,gd);
        cluster[oth] = rep;
        nscore[rep]  = __uint_as_float(sb);
        if (gs != gd){ valid[oth] = 0; partner[rep] = oth; }
        marked[ls] = 1; marked[ld] = 1;
      }
    }
    __syncthreads();
  }
}

// ---------- pool: new_x = relu((y[i]+y[partner]) * score * valid) ----------
template<int FO>
__global__ __launch_bounds__(256) void k_newx(const float* __restrict__ y, const int* __restrict__ partner,
    const float* __restrict__ nscore, const int* __restrict__ valid, float* __restrict__ out){
  constexpr int Q = (FO+63)/64;
  int lane = threadIdx.x & 63;
  int i = blockIdx.x*4 + (threadIdx.x>>6);
  int v = valid[i];
  float ns = nscore[i];
  int p = partner[i];
  const float* yi = y + (size_t)i*FO;
  const float* yp = (p>=0) ? (y + (size_t)p*FO) : yi;
  float* oi = out + (size_t)i*FO;
#pragma unroll
  for (int q=0;q<Q;q++){
    int c = lane + q*64;
    if (c<FO){
      float val = yi[c];
      if (p>=0) val += yp[c];
      val *= ns;
      oi[c] = v ? fmaxf(val,0.f) : 0.f;
    }
  }
}

// ---------- pool: remap edges + dedupe via per-graph key table ----------
__global__ void k_remap1(int* __restrict__ src, int* __restrict__ dst, const int* __restrict__ em,
                         const int* __restrict__ cluster, int* __restrict__ table){
  int e = blockIdx.x*256 + threadIdx.x;
  if (e<NE && em[e]){
    int ns = cluster[src[e]], nd = cluster[dst[e]];
    src[e]=ns; dst[e]=nd;
    int g = ns>>9;
    table[(g<<18) | ((ns&511)<<9) | (nd&511)] = 0x7FFFFFFF;
  }
}
__global__ void k_remap2(const int* __restrict__ src, const int* __restrict__ dst,
                         const int* __restrict__ em, int* __restrict__ table){
  int e = blockIdx.x*256 + threadIdx.x;
  if (e<NE && em[e]){
    int ns=src[e], nd=dst[e]; int g=ns>>9;
    atomicMin(&table[(g<<18) | ((ns&511)<<9) | (nd&511)], e);
  }
}
__global__ void k_remap3(const int* __restrict__ src, const int* __restrict__ dst,
                         int* __restrict__ em, const int* __restrict__ table){
  int e = blockIdx.x*256 + threadIdx.x;
  if (e<NE && em[e]){
    int ns=src[e], nd=dst[e]; int g=ns>>9;
    if (table[(g<<18) | ((ns&511)<<9) | (nd&511)] != e) em[e]=0;
  }
}

// ---------- readout ----------
__global__ __launch_bounds__(256) void k_gmax(const float* __restrict__ x, const int* __restrict__ valid,
                                              float* __restrict__ gbuf){
  int g = blockIdx.x;
  __shared__ int lv[PERG];
  for (int i=threadIdx.x;i<PERG;i+=256) lv[i] = valid[g*PERG+i];
  __syncthreads();
  const float* base = x + (size_t)g*PERG*600;
  for (int c=threadIdx.x; c<600; c+=256){
    float m = -1e30f;
    for (int r=0;r<PERG;r++)
      if (lv[r]) m = fmaxf(m, base[(size_t)r*600+c]);
    gbuf[g*600+c] = m;
  }
}
__global__ __launch_bounds__(256) void k_head(const float* __restrict__ gbuf,
    const float* __restrict__ L1w, const float* __restrict__ L1b,
    const float* __restrict__ L2w, const float* __restrict__ L2b,
    const float* __restrict__ L3w, const float* __restrict__ L3b, float* __restrict__ out){
  int g = blockIdx.x, t = threadIdx.x;
  __shared__ float gg[600];
  __shared__ float z1[200];
  __shared__ float z2[20];
  __shared__ float z3[4];
  for (int c=t;c<600;c+=256) gg[c] = gbuf[g*600+c];
  __syncthreads();
  if (t<200){
    float s = L1b[t];
    for (int k=0;k<600;k++) s += gg[k]*L1w[k*200+t];
    z1[t] = fmaxf(s,0.f);
  }
  __syncthreads();
  if (t<20){
    float s = L2b[t];
    for (int k=0;k<200;k++) s += z1[k]*L2w[k*20+t];
    z2[t] = fmaxf(s,0.f);
  }
  __syncthreads();
  if (t<4){
    float s = L3b[t];
    for (int k=0;k<20;k++) s += z2[k]*L3w[k*4+t];
    z3[t] = fmaxf(s,0.f);
  }
  __syncthreads();
  if (t==0){
    float m = fmaxf(fmaxf(z3[0],z3[1]), fmaxf(z3[2],z3[3]));
    float e0=expf(z3[0]-m), e1=expf(z3[1]-m), e2=expf(z3[2]-m), e3=expf(z3[3]-m);
    float s = e0+e1+e2+e3;
    out[g*4+0]=e0/s; out[g*4+1]=e1/s; out[g*4+2]=e2/s; out[g*4+3]=e3/s;
  }
}

// ---------- host orchestration ----------
struct WsPtrs {
  float *A, *B;
  int *src, *dst, *em;
  float *sc;
  int *elist;
  int *gpk; unsigned *gsb; int *geid;
  int *cnt, *rowp, *cursor;
  float *dinv, *selfco;
  int *hs;
  unsigned *mx;
  float *den, *aval, *bval;
  int *cluster; float *nscore; int *partner; int *valid;
  int *gcount;
  float *gbuf;
};

template<int FO>
static void run_layer(const WsPtrs& P, const float* xin, int K,
                      const float* Wm, const float* bias,
                      const float* Pw, const float* Pb,
                      float* hbuf, float* ybuf, hipStream_t stream){
  const int EG = NE/256;           // 1024 blocks for edge kernels
  const int NG4 = NN/4;            // 4096 blocks, wave per node
  const int NB = NN/256;           // 64 blocks for node kernels

  // h = x @ W
  dim3 gmm((FO+127)/128, NN/128);
  k_mm<<<gmm,256,0,stream>>>(xin, Wm, hbuf, NN, K, FO);

  // degree + CSR by dst
  hipMemsetAsync(P.cnt, 0, (NN+1)*sizeof(int), stream);
  hipMemsetAsync(P.hs,  0, NN*sizeof(int), stream);
  k_count<<<EG,256,0,stream>>>(P.src, P.dst, P.em, P.cnt, P.hs);
  k_scan<<<1,1024,0,stream>>>(P.cnt, P.rowp, P.cursor);
  k_fill<<<EG,256,0,stream>>>(P.dst, P.em, P.cursor, P.elist);
  k_nodeprep<<<NB,256,0,stream>>>(P.cnt, P.hs, P.dinv, P.selfco);

  // y = agg + selfco*h + b
  k_agg<FO><<<NG4,256,0,stream>>>(hbuf, P.rowp, P.elist, P.src, P.dinv, P.selfco, bias, ybuf);

  // edge scores (softmax grouped by dst)
  k_ab<FO><<<NG4,256,0,stream>>>(ybuf, Pw, P.aval, P.bval);
  hipMemsetAsync(P.mx,  0, NN*sizeof(unsigned), stream);
  k_raw<<<EG,256,0,stream>>>(P.src, P.dst, P.em, P.aval, P.bval, Pb, P.sc, P.mx);
  hipMemsetAsync(P.den, 0, NN*sizeof(float), stream);
  k_ex<<<EG,256,0,stream>>>(P.dst, P.em, P.sc, P.mx, P.den);
  k_score<<<EG,256,0,stream>>>(P.dst, P.em, P.sc, P.den);

  // matching
  hipMemsetAsync(P.gcount, 0, NGR*sizeof(int), stream);
  k_poolinit<<<NB,256,0,stream>>>(P.cluster, P.nscore, P.partner);
  k_build<<<EG,256,0,stream>>>(P.src, P.dst, P.em, P.sc, P.gcount, P.gpk, P.gsb, P.geid);
  k_match<<<NGR,256,0,stream>>>(P.gcount, P.gpk, P.gsb, P.geid, P.cluster, P.nscore, P.partner, P.valid);

  // pooled features (relu fused) -> hbuf
  k_newx<FO><<<NG4,256,0,stream>>>(ybuf, P.partner, P.nscore, P.valid, hbuf);

  // remap + dedupe (table lives in the now-dead ybuf)
  int* table = (int*)ybuf;
  k_remap1<<<EG,256,0,stream>>>(P.src, P.dst, P.em, P.cluster, table);
  k_remap2<<<EG,256,0,stream>>>(P.src, P.dst, P.em, table);
  k_remap3<<<EG,256,0,stream>>>(P.src, P.dst, P.em, table);
}

extern "C" void kernel_launch(void* const* d_in, const int* in_sizes, int n_in,
                              void* d_out, int out_size, void* d_ws, size_t ws_size,
                              hipStream_t stream){
  const float* x0  = (const float*)d_in[0];
  const int*   ei  = (const int*)  d_in[1];
  const float* W1  = (const float*)d_in[3];  const float* b1  = (const float*)d_in[4];
  const float* W2  = (const float*)d_in[5];  const float* b2  = (const float*)d_in[6];
  const float* W3  = (const float*)d_in[7];  const float* b3  = (const float*)d_in[8];
  const float* P1w = (const float*)d_in[9];  const float* P1b = (const float*)d_in[10];
  const float* P2w = (const float*)d_in[11]; const float* P2b = (const float*)d_in[12];
  const float* P3w = (const float*)d_in[13]; const float* P3b = (const float*)d_in[14];
  const float* L1w = (const float*)d_in[15]; const float* L1b = (const float*)d_in[16];
  const float* L2w = (const float*)d_in[17]; const float* L2b = (const float*)d_in[18];
  const float* L3w = (const float*)d_in[19]; const float* L3b = (const float*)d_in[20];
  float* out = (float*)d_out;

  char* w = (char*)d_ws;
  size_t off = 0;
  auto alloc = [&](size_t bytes)->void*{
    void* p = w + off;
    off += bytes;
    off = (off + 255) & ~(size_t)255;
    return p;
  };
  WsPtrs P;
  P.A     = (float*)alloc((size_t)NN*600*4);      // ping
  P.B     = (float*)alloc((size_t)NN*600*4);      // pong (also dedupe table home)
  P.src   = (int*)  alloc((size_t)NE*4);
  P.dst   = (int*)  alloc((size_t)NE*4);
  P.em    = (int*)  alloc((size_t)NE*4);
  P.sc    = (float*)alloc((size_t)NE*4);
  P.elist = (int*)  alloc((size_t)NE*4);
  P.gpk   = (int*)     alloc((size_t)NGR*GCAP*4);
  P.gsb   = (unsigned*)alloc((size_t)NGR*GCAP*4);
  P.geid  = (int*)     alloc((size_t)NGR*GCAP*4);
  P.cnt    = (int*)alloc((size_t)(NN+1)*4);
  P.rowp   = (int*)alloc((size_t)(NN+1)*4);
  P.cursor = (int*)alloc((size_t)(NN+1)*4);
  P.dinv   = (float*)alloc((size_t)NN*4);
  P.selfco = (float*)alloc((size_t)NN*4);
  P.hs     = (int*)  alloc((size_t)NN*4);
  P.mx     = (unsigned*)alloc((size_t)NN*4);
  P.den    = (float*)alloc((size_t)NN*4);
  P.aval   = (float*)alloc((size_t)NN*4);
  P.bval   = (float*)alloc((size_t)NN*4);
  P.cluster= (int*)  alloc((size_t)NN*4);
  P.nscore = (float*)alloc((size_t)NN*4);
  P.partner= (int*)  alloc((size_t)NN*4);
  P.valid  = (int*)  alloc((size_t)NN*4);
  P.gcount = (int*)  alloc((size_t)NGR*4);
  P.gbuf   = (float*)alloc((size_t)NGR*600*4);
  (void)ws_size; (void)in_sizes; (void)n_in; (void)out_size;

  // init edge copies + valid flags
  k_init_edges<<<NE/256,256,0,stream>>>(ei, P.src, P.dst, P.em);
  k_init_nodes<<<NN/256,256,0,stream>>>(P.valid);

  // layer 1: x0[16384,107] -> h A -> y B -> newx A (table in B)
  run_layer<200>(P, x0,  107, W1, b1, P1w, P1b, P.A, P.B, stream);
  // layer 2: x=A -> h B -> y A -> newx B (table in A)
  run_layer<400>(P, P.A, 200, W2, b2, P2w, P2b, P.B, P.A, stream);
  // layer 3: x=B -> h A -> y B -> newx A (table in B)
  run_layer<600>(P, P.B, 400, W3, b3, P3w, P3b, P.A, P.B, stream);

  // readout + MLP head + softmax
  k_gmax<<<NGR,256,0,stream>>>(P.A, P.valid, P.gbuf);
  k_head<<<NGR,256,0,stream>>>(P.gbuf, L1w, L1b, L2w, L2b, L3w, L3b, out);
}

// Round 3
// 2919.331 us; speedup vs baseline: 1.6468x; 1.6468x over previous
//
#include <hip/hip_runtime.h>

#define NN 16384
#define PERG 512
#define NGR 32
#define NE 262144
#define GCAP 16384

// ---------- helpers ----------
__device__ __forceinline__ unsigned encf(float f){
  unsigned u = __float_as_uint(f);
  return (u & 0x80000000u) ? ~u : (u | 0x80000000u);
}
__device__ __forceinline__ float decf(unsigned e){
  unsigned u = (e & 0x80000000u) ? (e ^ 0x80000000u) : ~e;
  return __uint_as_float(u);
}

// ---------- init ----------
__global__ void k_init_edges(const int* __restrict__ ei, int* __restrict__ src,
                             int* __restrict__ dst, int* __restrict__ em){
  int e = blockIdx.x*256 + threadIdx.x;
  if (e < NE){ src[e]=ei[e]; dst[e]=ei[NE+e]; em[e]=1; }
}
__global__ void k_init_nodes(int* __restrict__ valid){
  int i = blockIdx.x*256 + threadIdx.x;
  if (i < NN) valid[i]=1;
}

// ---------- dense matmul C[M,N] = A[M,K] @ W[K,N], f32 ----------
__global__ __launch_bounds__(256) void k_mm(const float* __restrict__ A, const float* __restrict__ W,
                                            float* __restrict__ C, int M, int K, int N){
  __shared__ float As[8][128];
  __shared__ float Ws[8][128];
  int col0 = blockIdx.x*128, row0 = blockIdx.y*128;
  int t = threadIdx.x, tx = t & 15, ty = t >> 4;
  float acc[8][8];
#pragma unroll
  for (int i=0;i<8;i++)
#pragma unroll
    for (int j=0;j<8;j++) acc[i][j]=0.f;
  for (int k0=0; k0<K; k0+=8){
#pragma unroll
    for (int i=0;i<4;i++){
      int idx = t*4+i; int m = idx>>3, kk = idx&7;
      As[kk][m] = (k0+kk<K) ? A[(size_t)(row0+m)*K + (k0+kk)] : 0.f;
    }
#pragma unroll
    for (int i=0;i<4;i++){
      int idx = t*4+i; int kk = idx>>7, nn = idx&127;
      Ws[kk][nn] = (k0+kk<K && col0+nn<N) ? W[(size_t)(k0+kk)*N + (col0+nn)] : 0.f;
    }
    __syncthreads();
#pragma unroll
    for (int kk=0;kk<8;kk++){
      float a[8], b[8];
#pragma unroll
      for (int i=0;i<4;i++){
        a[i]   = As[kk][ty*4+i];  a[4+i] = As[kk][64+ty*4+i];
        b[i]   = Ws[kk][tx*4+i];  b[4+i] = Ws[kk][64+tx*4+i];
      }
#pragma unroll
      for (int i=0;i<8;i++)
#pragma unroll
        for (int j=0;j<8;j++) acc[i][j] += a[i]*b[j];
    }
    __syncthreads();
  }
#pragma unroll
  for (int i=0;i<8;i++){
    int r = row0 + ((i<4)? ty*4+i : 64+ty*4+(i-4));
#pragma unroll
    for (int j=0;j<8;j++){
      int cc = col0 + ((j<4)? tx*4+j : 64+tx*4+(j-4));
      if (cc<N) C[(size_t)r*N+cc] = acc[i][j];
    }
  }
}

// ---------- degree / CSR ----------
__global__ void k_count(const int* __restrict__ src, const int* __restrict__ dst,
                        const int* __restrict__ em, int* __restrict__ cnt, int* __restrict__ hs){
  int e = blockIdx.x*256 + threadIdx.x;
  if (e<NE && em[e]){
    atomicAdd(&cnt[dst[e]], 1);
    if (src[e]==dst[e]) hs[dst[e]] = 1;
  }
}
__global__ __launch_bounds__(1024) void k_scan(const int* __restrict__ cnt, int* __restrict__ rowp,
                                               int* __restrict__ cursor){
  __shared__ int part[1024];
  int t = threadIdx.x;
  int base = t*16;
  int loc[16];
  int s = 0;
#pragma unroll
  for (int i=0;i<16;i++){ loc[i]=s; s += cnt[base+i]; }
  part[t] = s;
  __syncthreads();
  for (int off=1; off<1024; off<<=1){
    int v = (t>=off) ? part[t-off] : 0;
    __syncthreads();
    part[t] += v;
    __syncthreads();
  }
  int excl = (t==0) ? 0 : part[t-1];
#pragma unroll
  for (int i=0;i<16;i++){ int v = excl + loc[i]; rowp[base+i]=v; cursor[base+i]=v; }
  if (t==1023){ rowp[NN]=part[1023]; cursor[NN]=part[1023]; }
}
__global__ void k_fill(const int* __restrict__ dst, const int* __restrict__ em,
                       int* __restrict__ cursor, int* __restrict__ elist){
  int e = blockIdx.x*256 + threadIdx.x;
  if (e<NE && em[e]) elist[atomicAdd(&cursor[dst[e]],1)] = e;
}
__global__ void k_nodeprep(const int* __restrict__ cnt, const int* __restrict__ hs,
                           float* __restrict__ dinv, float* __restrict__ selfco){
  int i = blockIdx.x*256 + threadIdx.x;
  if (i<NN){
    float deg = (float)cnt[i] + (hs[i] ? 0.f : 1.f);
    dinv[i]   = rsqrtf(deg);
    selfco[i] = hs[i] ? 0.f : (1.f/deg);
  }
}

// ---------- GCN aggregation: y = agg + selfco*h + b (wave per node) ----------
template<int FO>
__global__ __launch_bounds__(256) void k_agg(const float* __restrict__ h, const int* __restrict__ rowp,
    const int* __restrict__ elist, const int* __restrict__ src, const float* __restrict__ dinv,
    const float* __restrict__ selfco, const float* __restrict__ bias, float* __restrict__ y){
  constexpr int Q = (FO+63)/64;
  int lane = threadIdx.x & 63;
  int i = blockIdx.x*4 + (threadIdx.x>>6);
  float acc[Q];
#pragma unroll
  for (int q=0;q<Q;q++) acc[q]=0.f;
  int s0 = rowp[i], s1 = rowp[i+1];
  float di = dinv[i];
  for (int p=s0; p<s1; p++){
    int e = elist[p]; int s = src[e];
    float nr = di * dinv[s];
    const float* hrow = h + (size_t)s*FO;
#pragma unroll
    for (int q=0;q<Q;q++){ int c=lane+q*64; if (c<FO) acc[q] += nr*hrow[c]; }
  }
  float sc = selfco[i];
  const float* hi = h + (size_t)i*FO;
  float* yi = y + (size_t)i*FO;
#pragma unroll
  for (int q=0;q<Q;q++){ int c=lane+q*64; if (c<FO) yi[c] = acc[q] + sc*hi[c] + bias[c]; }
}

// ---------- pool: per-node score partials ----------
template<int FO>
__global__ __launch_bounds__(256) void k_ab(const float* __restrict__ y, const float* __restrict__ Pw,
                                            float* __restrict__ aval, float* __restrict__ bval){
  constexpr int Q = (FO+63)/64;
  int lane = threadIdx.x & 63;
  int i = blockIdx.x*4 + (threadIdx.x>>6);
  const float* yi = y + (size_t)i*FO;
  float sa=0.f, sb=0.f;
#pragma unroll
  for (int q=0;q<Q;q++){ int c=lane+q*64; if (c<FO){ float v=yi[c]; sa += v*Pw[c]; sb += v*Pw[FO+c]; } }
  for (int o=32;o;o>>=1){ sa += __shfl_xor(sa,o); sb += __shfl_xor(sb,o); }
  if (lane==0){ aval[i]=sa; bval[i]=sb; }
}
__global__ void k_raw(const int* __restrict__ src, const int* __restrict__ dst, const int* __restrict__ em,
                      const float* __restrict__ aval, const float* __restrict__ bval,
                      const float* __restrict__ Pb, float* __restrict__ sc, unsigned* __restrict__ mx){
  int e = blockIdx.x*256 + threadIdx.x;
  if (e<NE && em[e]){
    float r = aval[src[e]] + bval[dst[e]] + Pb[0];
    sc[e] = r;
    atomicMax(&mx[dst[e]], encf(r));
  }
}
__global__ void k_ex(const int* __restrict__ dst, const int* __restrict__ em, float* __restrict__ sc,
                     const unsigned* __restrict__ mx, float* __restrict__ den){
  int e = blockIdx.x*256 + threadIdx.x;
  if (e<NE && em[e]){
    float ex = expf(sc[e] - decf(mx[dst[e]]));
    sc[e] = ex;
    atomicAdd(&den[dst[e]], ex);
  }
}
__global__ void k_score(const int* __restrict__ dst, const int* __restrict__ em,
                        float* __restrict__ sc, const float* __restrict__ den){
  int e = blockIdx.x*256 + threadIdx.x;
  if (e<NE && em[e]) sc[e] = sc[e]/fmaxf(den[dst[e]],1e-16f) + 0.1f;
}

// ---------- pool: per-node init ----------
__global__ void k_poolinit(int* __restrict__ cluster, float* __restrict__ nscore, int* __restrict__ partner){
  int i = blockIdx.x*256 + threadIdx.x;
  if (i<NN){ cluster[i]=i; nscore[i]=1.f; partner[i]=-1; }
}

// ---------- pool: build per-graph edge lists ----------
__global__ void k_build(const int* __restrict__ src, const int* __restrict__ dst, const int* __restrict__ em,
                        const float* __restrict__ sc, int* __restrict__ gcount,
                        int* __restrict__ gpk, unsigned* __restrict__ gsb, int* __restrict__ geid){
  int e = blockIdx.x*256 + threadIdx.x;
  if (e<NE && em[e]){
    int s = src[e], d = dst[e];
    int g = s >> 9;
    int slot = atomicAdd(&gcount[g],1);
    if (slot < GCAP){
      int b = g*GCAP + slot;
      gpk[b]  = ((s&511)<<9) | (d&511);
      gsb[b]  = __float_as_uint(sc[e]);   // score > 0 -> bits are order-preserving
      geid[b] = e;
    }
  }
}

// ---------- pool: greedy matching; edges in REGISTERS, state in LDS ----------
// priority = (score_bits << 18) | (0x3FFFF - eid)  -> max = (max score, min eid)
#define NEPT 16   // edges per thread: 16 * 1024 = 16384 = GCAP
__global__ __launch_bounds__(1024) void k_match(const int* __restrict__ gcount, const int* __restrict__ gpk,
    const unsigned* __restrict__ gsb, const int* __restrict__ geid,
    int* __restrict__ cluster, float* __restrict__ nscore, int* __restrict__ partner, int* __restrict__ valid){
  int g = blockIdx.x;
  __shared__ unsigned long long best[PERG];   // 4 KB
  __shared__ unsigned char marked[PERG];
  __shared__ int flag;
  int t = threadIdx.x;
  for (int i=t;i<PERG;i+=1024) marked[i] = valid[g*PERG+i] ? 0 : 1;
  int nE = min(gcount[g], GCAP);
  int base = g*GCAP;

  // load this thread's edges into registers (coalesced, strided by 1024)
  unsigned long long priR[NEPT];
  unsigned pkR[NEPT];
  unsigned live = 0u;
#pragma unroll
  for (int j=0;j<NEPT;j++){
    int k = t + j*1024;
    if (k < nE){
      pkR[j] = (unsigned)gpk[base+k];
      unsigned sb  = gsb[base+k];
      unsigned eid = (unsigned)geid[base+k];
      priR[j] = ((unsigned long long)sb << 18) | (unsigned long long)(0x3FFFFu - eid);
      live |= (1u<<j);
    } else { priR[j]=0ull; pkR[j]=0u; }
  }

  for (int round=0; round<512; ++round){
    for (int i=t;i<PERG;i+=1024) best[i]=0ull;
    if (t==0) flag = 0;
    __syncthreads();
    // pass 1: local-max
    int any = 0;
#pragma unroll
    for (int j=0;j<NEPT;j++){
      if (!(live & (1u<<j))) continue;
      unsigned pk = pkR[j]; int ls = pk>>9, ld = pk&511;
      if (marked[ls] | marked[ld]){ live &= ~(1u<<j); continue; }
      any = 1;
      atomicMax(&best[ls], priR[j]);
      if (ld != ls) atomicMax(&best[ld], priR[j]);
    }
    if (any) flag = 1;
    __syncthreads();
    if (!flag) break;
    // pass 2: commit winners (priorities unique -> no conflicts)
#pragma unroll
    for (int j=0;j<NEPT;j++){
      if (!(live & (1u<<j))) continue;
      unsigned pk = pkR[j]; int ls = pk>>9, ld = pk&511;
      unsigned long long p = priR[j];
      if (best[ls]==p && best[ld]==p){
        int gs = g*PERG+ls, gd = g*PERG+ld;
        int rep = min(gs,gd), oth = max(gs,gd);
        unsigned sb = (unsigned)(p >> 18);
        cluster[oth] = rep;
        nscore[rep]  = __uint_as_float(sb);
        if (gs != gd){ valid[oth] = 0; partner[rep] = oth; }
        marked[ls] = 1; marked[ld] = 1;
        live &= ~(1u<<j);
      }
    }
    __syncthreads();
  }
}

// ---------- pool: new_x = relu((y[i]+y[partner]) * score * valid) ----------
template<int FO>
__global__ __launch_bounds__(256) void k_newx(const float* __restrict__ y, const int* __restrict__ partner,
    const float* __restrict__ nscore, const int* __restrict__ valid, float* __restrict__ out){
  constexpr int Q = (FO+63)/64;
  int lane = threadIdx.x & 63;
  int i = blockIdx.x*4 + (threadIdx.x>>6);
  int v = valid[i];
  float ns = nscore[i];
  int p = partner[i];
  const float* yi = y + (size_t)i*FO;
  const float* yp = (p>=0) ? (y + (size_t)p*FO) : yi;
  float* oi = out + (size_t)i*FO;
#pragma unroll
  for (int q=0;q<Q;q++){
    int c = lane + q*64;
    if (c<FO){
      float val = yi[c];
      if (p>=0) val += yp[c];
      val *= ns;
      oi[c] = v ? fmaxf(val,0.f) : 0.f;
    }
  }
}

// ---------- pool: remap edges + dedupe via per-graph key table ----------
__global__ void k_remap1(int* __restrict__ src, int* __restrict__ dst, const int* __restrict__ em,
                         const int* __restrict__ cluster, int* __restrict__ table){
  int e = blockIdx.x*256 + threadIdx.x;
  if (e<NE && em[e]){
    int ns = cluster[src[e]], nd = cluster[dst[e]];
    src[e]=ns; dst[e]=nd;
    int g = ns>>9;
    table[(g<<18) | ((ns&511)<<9) | (nd&511)] = 0x7FFFFFFF;
  }
}
__global__ void k_remap2(const int* __restrict__ src, const int* __restrict__ dst,
                         const int* __restrict__ em, int* __restrict__ table){
  int e = blockIdx.x*256 + threadIdx.x;
  if (e<NE && em[e]){
    int ns=src[e], nd=dst[e]; int g=ns>>9;
    atomicMin(&table[(g<<18) | ((ns&511)<<9) | (nd&511)], e);
  }
}
__global__ void k_remap3(const int* __restrict__ src, const int* __restrict__ dst,
                         int* __restrict__ em, const int* __restrict__ table){
  int e = blockIdx.x*256 + threadIdx.x;
  if (e<NE && em[e]){
    int ns=src[e], nd=dst[e]; int g=ns>>9;
    if (table[(g<<18) | ((ns&511)<<9) | (nd&511)] != e) em[e]=0;
  }
}

// ---------- readout ----------
__global__ __launch_bounds__(256) void k_gmax(const float* __restrict__ x, const int* __restrict__ valid,
                                              float* __restrict__ gbuf){
  int g = blockIdx.x;
  __shared__ int lv[PERG];
  for (int i=threadIdx.x;i<PERG;i+=256) lv[i] = valid[g*PERG+i];
  __syncthreads();
  const float* base = x + (size_t)g*PERG*600;
  for (int c=threadIdx.x; c<600; c+=256){
    float m = -1e30f;
    for (int r=0;r<PERG;r++)
      if (lv[r]) m = fmaxf(m, base[(size_t)r*600+c]);
    gbuf[g*600+c] = m;
  }
}
__global__ __launch_bounds__(256) void k_head(const float* __restrict__ gbuf,
    const float* __restrict__ L1w, const float* __restrict__ L1b,
    const float* __restrict__ L2w, const float* __restrict__ L2b,
    const float* __restrict__ L3w, const float* __restrict__ L3b, float* __restrict__ out){
  int g = blockIdx.x, t = threadIdx.x;
  __shared__ float gg[600];
  __shared__ float z1[200];
  __shared__ float z2[20];
  __shared__ float z3[4];
  for (int c=t;c<600;c+=256) gg[c] = gbuf[g*600+c];
  __syncthreads();
  if (t<200){
    float s = L1b[t];
    for (int k=0;k<600;k++) s += gg[k]*L1w[k*200+t];
    z1[t] = fmaxf(s,0.f);
  }
  __syncthreads();
  if (t<20){
    float s = L2b[t];
    for (int k=0;k<200;k++) s += z1[k]*L2w[k*20+t];
    z2[t] = fmaxf(s,0.f);
  }
  __syncthreads();
  if (t<4){
    float s = L3b[t];
    for (int k=0;k<20;k++) s += z2[k]*L3w[k*4+t];
    z3[t] = fmaxf(s,0.f);
  }
  __syncthreads();
  if (t==0){
    float m = fmaxf(fmaxf(z3[0],z3[1]), fmaxf(z3[2],z3[3]));
    float e0=expf(z3[0]-m), e1=expf(z3[1]-m), e2=expf(z3[2]-m), e3=expf(z3[3]-m);
    float s = e0+e1+e2+e3;
    out[g*4+0]=e0/s; out[g*4+1]=e1/s; out[g*4+2]=e2/s; out[g*4+3]=e3/s;
  }
}

// ---------- host orchestration ----------
struct WsPtrs {
  float *A, *B;
  int *src, *dst, *em;
  float *sc;
  int *elist;
  int *gpk; unsigned *gsb; int *geid;
  int *cnt, *rowp, *cursor;
  float *dinv, *selfco;
  int *hs;
  unsigned *mx;
  float *den, *aval, *bval;
  int *cluster; float *nscore; int *partner; int *valid;
  int *gcount;
  float *gbuf;
};

template<int FO>
static void run_layer(const WsPtrs& P, const float* xin, int K,
                      const float* Wm, const float* bias,
                      const float* Pw, const float* Pb,
                      float* hbuf, float* ybuf, hipStream_t stream){
  const int EG = NE/256;           // 1024 blocks for edge kernels
  const int NG4 = NN/4;            // 4096 blocks, wave per node
  const int NB = NN/256;           // 64 blocks for node kernels

  // h = x @ W
  dim3 gmm((FO+127)/128, NN/128);
  k_mm<<<gmm,256,0,stream>>>(xin, Wm, hbuf, NN, K, FO);

  // degree + CSR by dst
  hipMemsetAsync(P.cnt, 0, (NN+1)*sizeof(int), stream);
  hipMemsetAsync(P.hs,  0, NN*sizeof(int), stream);
  k_count<<<EG,256,0,stream>>>(P.src, P.dst, P.em, P.cnt, P.hs);
  k_scan<<<1,1024,0,stream>>>(P.cnt, P.rowp, P.cursor);
  k_fill<<<EG,256,0,stream>>>(P.dst, P.em, P.cursor, P.elist);
  k_nodeprep<<<NB,256,0,stream>>>(P.cnt, P.hs, P.dinv, P.selfco);

  // y = agg + selfco*h + b
  k_agg<FO><<<NG4,256,0,stream>>>(hbuf, P.rowp, P.elist, P.src, P.dinv, P.selfco, bias, ybuf);

  // edge scores (softmax grouped by dst)
  k_ab<FO><<<NG4,256,0,stream>>>(ybuf, Pw, P.aval, P.bval);
  hipMemsetAsync(P.mx,  0, NN*sizeof(unsigned), stream);
  k_raw<<<EG,256,0,stream>>>(P.src, P.dst, P.em, P.aval, P.bval, Pb, P.sc, P.mx);
  hipMemsetAsync(P.den, 0, NN*sizeof(float), stream);
  k_ex<<<EG,256,0,stream>>>(P.dst, P.em, P.sc, P.mx, P.den);
  k_score<<<EG,256,0,stream>>>(P.dst, P.em, P.sc, P.den);

  // matching
  hipMemsetAsync(P.gcount, 0, NGR*sizeof(int), stream);
  k_poolinit<<<NB,256,0,stream>>>(P.cluster, P.nscore, P.partner);
  k_build<<<EG,256,0,stream>>>(P.src, P.dst, P.em, P.sc, P.gcount, P.gpk, P.gsb, P.geid);
  k_match<<<NGR,1024,0,stream>>>(P.gcount, P.gpk, P.gsb, P.geid, P.cluster, P.nscore, P.partner, P.valid);

  // pooled features (relu fused) -> hbuf
  k_newx<FO><<<NG4,256,0,stream>>>(ybuf, P.partner, P.nscore, P.valid, hbuf);

  // remap + dedupe (table lives in the now-dead ybuf)
  int* table = (int*)ybuf;
  k_remap1<<<EG,256,0,stream>>>(P.src, P.dst, P.em, P.cluster, table);
  k_remap2<<<EG,256,0,stream>>>(P.src, P.dst, P.em, table);
  k_remap3<<<EG,256,0,stream>>>(P.src, P.dst, P.em, table);
}

extern "C" void kernel_launch(void* const* d_in, const int* in_sizes, int n_in,
                              void* d_out, int out_size, void* d_ws, size_t ws_size,
                              hipStream_t stream){
  const float* x0  = (const float*)d_in[0];
  const int*   ei  = (const int*)  d_in[1];
  const float* W1  = (const float*)d_in[3];  const float* b1  = (const float*)d_in[4];
  const float* W2  = (const float*)d_in[5];  const float* b2  = (const float*)d_in[6];
  const float* W3  = (const float*)d_in[7];  const float* b3  = (const float*)d_in[8];
  const float* P1w = (const float*)d_in[9];  const float* P1b = (const float*)d_in[10];
  const float* P2w = (const float*)d_in[11]; const float* P2b = (const float*)d_in[12];
  const float* P3w = (const float*)d_in[13]; const float* P3b = (const float*)d_in[14];
  const float* L1w = (const float*)d_in[15]; const float* L1b = (const float*)d_in[16];
  const float* L2w = (const float*)d_in[17]; const float* L2b = (const float*)d_in[18];
  const float* L3w = (const float*)d_in[19]; const float* L3b = (const float*)d_in[20];
  float* out = (float*)d_out;

  char* w = (char*)d_ws;
  size_t off = 0;
  auto alloc = [&](size_t bytes)->void*{
    void* p = w + off;
    off += bytes;
    off = (off + 255) & ~(size_t)255;
    return p;
  };
  WsPtrs P;
  P.A     = (float*)alloc((size_t)NN*600*4);      // ping
  P.B     = (float*)alloc((size_t)NN*600*4);      // pong (also dedupe table home)
  P.src   = (int*)  alloc((size_t)NE*4);
  P.dst   = (int*)  alloc((size_t)NE*4);
  P.em    = (int*)  alloc((size_t)NE*4);
  P.sc    = (float*)alloc((size_t)NE*4);
  P.elist = (int*)  alloc((size_t)NE*4);
  P.gpk   = (int*)     alloc((size_t)NGR*GCAP*4);
  P.gsb   = (unsigned*)alloc((size_t)NGR*GCAP*4);
  P.geid  = (int*)     alloc((size_t)NGR*GCAP*4);
  P.cnt    = (int*)alloc((size_t)(NN+1)*4);
  P.rowp   = (int*)alloc((size_t)(NN+1)*4);
  P.cursor = (int*)alloc((size_t)(NN+1)*4);
  P.dinv   = (float*)alloc((size_t)NN*4);
  P.selfco = (float*)alloc((size_t)NN*4);
  P.hs     = (int*)  alloc((size_t)NN*4);
  P.mx     = (unsigned*)alloc((size_t)NN*4);
  P.den    = (float*)alloc((size_t)NN*4);
  P.aval   = (float*)alloc((size_t)NN*4);
  P.bval   = (float*)alloc((size_t)NN*4);
  P.cluster= (int*)  alloc((size_t)NN*4);
  P.nscore = (float*)alloc((size_t)NN*4);
  P.partner= (int*)  alloc((size_t)NN*4);
  P.valid  = (int*)  alloc((size_t)NN*4);
  P.gcount = (int*)  alloc((size_t)NGR*4);
  P.gbuf   = (float*)alloc((size_t)NGR*600*4);
  (void)ws_size; (void)in_sizes; (void)n_in; (void)out_size;

  // init edge copies + valid flags
  k_init_edges<<<NE/256,256,0,stream>>>(ei, P.src, P.dst, P.em);
  k_init_nodes<<<NN/256,256,0,stream>>>(P.valid);

  // layer 1: x0[16384,107] -> h A -> y B -> newx A (table in B)
  run_layer<200>(P, x0,  107, W1, b1, P1w, P1b, P.A, P.B, stream);
  // layer 2: x=A -> h B -> y A -> newx B (table in A)
  run_layer<400>(P, P.A, 200, W2, b2, P2w, P2b, P.B, P.A, stream);
  // layer 3: x=B -> h A -> y B -> newx A (table in B)
  run_layer<600>(P, P.B, 400, W3, b3, P3w, P3b, P.A, P.B, stream);

  // readout + MLP head + softmax
  k_gmax<<<NGR,256,0,stream>>>(P.A, P.valid, P.gbuf);
  k_head<<<NGR,256,0,stream>>>(P.gbuf, L1w, L1b, L2w, L2b, L3w, L3b, out);
}

// Round 4
// 1292.945 us; speedup vs baseline: 3.7182x; 2.2579x over previous
//
#include <hip/hip_runtime.h>

#define NN 16384
#define PERG 512
#define NGR 32
#define NE 262144
#define GSEG 9216            // per-graph edge segment capacity (E/NGR=8192 avg, +12% slack)
#define GBLK 36              // GSEG/256
#define EGRID (NGR*GBLK)     // 1152 blocks for bucketed edge kernels

// ---------- one-time bucketing: edges -> graph-major segments ----------
// graph of an edge never changes across layers (contraction stays in-graph)
__global__ __launch_bounds__(256) void k_bucket(const int* __restrict__ ei, int* __restrict__ gcount,
    int* __restrict__ bsrc, int* __restrict__ bdst, int* __restrict__ bem, int* __restrict__ beid){
  __shared__ int cnt[NGR];
  __shared__ int base[NGR];
  int t = threadIdx.x;
  if (t < NGR) cnt[t] = 0;
  __syncthreads();
  int e = blockIdx.x*256 + t;
  int s=0,d=0,g=0,r=0;
  bool ok = (e < NE);
  if (ok){ s = ei[e]; d = ei[NE+e]; g = s >> 9; r = atomicAdd(&cnt[g],1); }
  __syncthreads();
  if (t < NGR) base[t] = atomicAdd(&gcount[t], cnt[t]);   // 32 global atomics/block
  __syncthreads();
  if (ok){
    int pos = g*GSEG + base[g] + r;
    bsrc[pos]=s; bdst[pos]=d; bem[pos]=1; beid[pos]=e;
  }
}
__global__ void k_init_nodes(int* __restrict__ valid){
  int i = blockIdx.x*256 + threadIdx.x;
  if (i < NN) valid[i]=1;
}

// ---------- dense matmul C[M,N] = A[M,K] @ W[K,N], f32 ----------
__global__ __launch_bounds__(256) void k_mm(const float* __restrict__ A, const float* __restrict__ W,
                                            float* __restrict__ C, int M, int K, int N){
  __shared__ float As[8][128];
  __shared__ float Ws[8][128];
  int col0 = blockIdx.x*128, row0 = blockIdx.y*128;
  int t = threadIdx.x, tx = t & 15, ty = t >> 4;
  float acc[8][8];
#pragma unroll
  for (int i=0;i<8;i++)
#pragma unroll
    for (int j=0;j<8;j++) acc[i][j]=0.f;
  for (int k0=0; k0<K; k0+=8){
#pragma unroll
    for (int i=0;i<4;i++){
      int idx = t*4+i; int m = idx>>3, kk = idx&7;
      As[kk][m] = (k0+kk<K) ? A[(size_t)(row0+m)*K + (k0+kk)] : 0.f;
    }
#pragma unroll
    for (int i=0;i<4;i++){
      int idx = t*4+i; int kk = idx>>7, nn = idx&127;
      Ws[kk][nn] = (k0+kk<K && col0+nn<N) ? W[(size_t)(k0+kk)*N + (col0+nn)] : 0.f;
    }
    __syncthreads();
#pragma unroll
    for (int kk=0;kk<8;kk++){
      float a[8], b[8];
#pragma unroll
      for (int i=0;i<4;i++){
        a[i]   = As[kk][ty*4+i];  a[4+i] = As[kk][64+ty*4+i];
        b[i]   = Ws[kk][tx*4+i];  b[4+i] = Ws[kk][64+tx*4+i];
      }
#pragma unroll
      for (int i=0;i<8;i++)
#pragma unroll
        for (int j=0;j<8;j++) acc[i][j] += a[i]*b[j];
    }
    __syncthreads();
  }
#pragma unroll
  for (int i=0;i<8;i++){
    int r = row0 + ((i<4)? ty*4+i : 64+ty*4+(i-4));
#pragma unroll
    for (int j=0;j<8;j++){
      int cc = col0 + ((j<4)? tx*4+j : 64+tx*4+(j-4));
      if (cc<N) C[(size_t)r*N+cc] = acc[i][j];
    }
  }
}

// ---------- degree / CSR (bucketed edge space) ----------
__global__ void k_count(const int* __restrict__ bsrc, const int* __restrict__ bdst,
                        const int* __restrict__ bem, const int* __restrict__ gcnt,
                        int* __restrict__ cnt, int* __restrict__ hs){
  int g = blockIdx.x / GBLK; int k = (blockIdx.x % GBLK)*256 + threadIdx.x;
  if (k >= gcnt[g]) return;
  int e = g*GSEG + k;
  if (bem[e]){
    atomicAdd(&cnt[bdst[e]], 1);
    if (bsrc[e]==bdst[e]) hs[bdst[e]] = 1;
  }
}
__global__ __launch_bounds__(1024) void k_scan(const int* __restrict__ cnt, int* __restrict__ rowp,
                                               int* __restrict__ cursor){
  __shared__ int part[1024];
  int t = threadIdx.x;
  int base = t*16;
  int loc[16];
  int s = 0;
#pragma unroll
  for (int i=0;i<16;i++){ loc[i]=s; s += cnt[base+i]; }
  part[t] = s;
  __syncthreads();
  for (int off=1; off<1024; off<<=1){
    int v = (t>=off) ? part[t-off] : 0;
    __syncthreads();
    part[t] += v;
    __syncthreads();
  }
  int excl = (t==0) ? 0 : part[t-1];
#pragma unroll
  for (int i=0;i<16;i++){ int v = excl + loc[i]; rowp[base+i]=v; cursor[base+i]=v; }
  if (t==1023){ rowp[NN]=part[1023]; cursor[NN]=part[1023]; }
}
__global__ void k_fill(const int* __restrict__ bdst, const int* __restrict__ bem,
                       const int* __restrict__ gcnt, int* __restrict__ cursor, int* __restrict__ elist){
  int g = blockIdx.x / GBLK; int k = (blockIdx.x % GBLK)*256 + threadIdx.x;
  if (k >= gcnt[g]) return;
  int e = g*GSEG + k;
  if (bem[e]) elist[atomicAdd(&cursor[bdst[e]],1)] = e;
}
__global__ void k_nodeprep(const int* __restrict__ cnt, const int* __restrict__ hs,
                           float* __restrict__ dinv, float* __restrict__ selfco){
  int i = blockIdx.x*256 + threadIdx.x;
  if (i<NN){
    float deg = (float)cnt[i] + (hs[i] ? 0.f : 1.f);
    dinv[i]   = rsqrtf(deg);
    selfco[i] = hs[i] ? 0.f : (1.f/deg);
  }
}

// ---------- GCN aggregation: y = agg + selfco*h + b (wave per node) ----------
// XCD swizzle: blockIdx round-robins over 8 XCDs; map so each XCD owns 4
// contiguous graphs -> gathered h rows (0.4-2.4 MB/graph) stay in that XCD's L2.
template<int FO>
__global__ __launch_bounds__(256) void k_agg(const float* __restrict__ h, const int* __restrict__ rowp,
    const int* __restrict__ elist, const int* __restrict__ bsrc, const float* __restrict__ dinv,
    const float* __restrict__ selfco, const float* __restrict__ bias, float* __restrict__ y){
  constexpr int Q = (FO+63)/64;
  int lane = threadIdx.x & 63;
  int nblk = (blockIdx.x & 7)*512 + (blockIdx.x >> 3);   // 4096 blocks -> bijective
  int i = nblk*4 + (threadIdx.x>>6);
  float acc[Q];
#pragma unroll
  for (int q=0;q<Q;q++) acc[q]=0.f;
  int s0 = rowp[i], s1 = rowp[i+1];
  float di = dinv[i];
  for (int p=s0; p<s1; p++){
    int e = elist[p]; int s = bsrc[e];
    float nr = di * dinv[s];
    const float* hrow = h + (size_t)s*FO;
#pragma unroll
    for (int q=0;q<Q;q++){ int c=lane+q*64; if (c<FO) acc[q] += nr*hrow[c]; }
  }
  float sc = selfco[i];
  const float* hi = h + (size_t)i*FO;
  float* yi = y + (size_t)i*FO;
#pragma unroll
  for (int q=0;q<Q;q++){ int c=lane+q*64; if (c<FO) yi[c] = acc[q] + sc*hi[c] + bias[c]; }
}

// ---------- pool: per-node score partials ----------
template<int FO>
__global__ __launch_bounds__(256) void k_ab(const float* __restrict__ y, const float* __restrict__ Pw,
                                            float* __restrict__ aval, float* __restrict__ bval){
  constexpr int Q = (FO+63)/64;
  int lane = threadIdx.x & 63;
  int i = blockIdx.x*4 + (threadIdx.x>>6);
  const float* yi = y + (size_t)i*FO;
  float sa=0.f, sb=0.f;
#pragma unroll
  for (int q=0;q<Q;q++){ int c=lane+q*64; if (c<FO){ float v=yi[c]; sa += v*Pw[c]; sb += v*Pw[FO+c]; } }
  for (int o=32;o;o>>=1){ sa += __shfl_xor(sa,o); sb += __shfl_xor(sb,o); }
  if (lane==0){ aval[i]=sa; bval[i]=sb; }
}
__device__ __forceinline__ unsigned encf(float f){
  unsigned u = __float_as_uint(f);
  return (u & 0x80000000u) ? ~u : (u | 0x80000000u);
}
__device__ __forceinline__ float decf(unsigned e){
  unsigned u = (e & 0x80000000u) ? (e ^ 0x80000000u) : ~e;
  return __uint_as_float(u);
}
__global__ void k_raw(const int* __restrict__ bsrc, const int* __restrict__ bdst, const int* __restrict__ bem,
                      const int* __restrict__ gcnt,
                      const float* __restrict__ aval, const float* __restrict__ bval,
                      const float* __restrict__ Pb, float* __restrict__ sc, unsigned* __restrict__ mx){
  int g = blockIdx.x / GBLK; int k = (blockIdx.x % GBLK)*256 + threadIdx.x;
  if (k >= gcnt[g]) return;
  int e = g*GSEG + k;
  if (bem[e]){
    float r = aval[bsrc[e]] + bval[bdst[e]] + Pb[0];
    sc[e] = r;
    atomicMax(&mx[bdst[e]], encf(r));
  }
}
__global__ void k_ex(const int* __restrict__ bdst, const int* __restrict__ bem,
                     const int* __restrict__ gcnt, float* __restrict__ sc,
                     const unsigned* __restrict__ mx, float* __restrict__ den){
  int g = blockIdx.x / GBLK; int k = (blockIdx.x % GBLK)*256 + threadIdx.x;
  if (k >= gcnt[g]) return;
  int e = g*GSEG + k;
  if (bem[e]){
    float ex = expf(sc[e] - decf(mx[bdst[e]]));
    sc[e] = ex;
    atomicAdd(&den[bdst[e]], ex);
  }
}
__global__ void k_score(const int* __restrict__ bdst, const int* __restrict__ bem,
                        const int* __restrict__ gcnt,
                        float* __restrict__ sc, const float* __restrict__ den){
  int g = blockIdx.x / GBLK; int k = (blockIdx.x % GBLK)*256 + threadIdx.x;
  if (k >= gcnt[g]) return;
  int e = g*GSEG + k;
  if (bem[e]) sc[e] = sc[e]/fmaxf(den[bdst[e]],1e-16f) + 0.1f;
}

// ---------- pool: per-node init ----------
__global__ void k_poolinit(int* __restrict__ cluster, float* __restrict__ nscore, int* __restrict__ partner){
  int i = blockIdx.x*256 + threadIdx.x;
  if (i<NN){ cluster[i]=i; nscore[i]=1.f; partner[i]=-1; }
}

// ---------- pool: greedy matching; edges in REGISTERS, state in LDS ----------
// priority = (score_bits << 18) | (0x3FFFF - orig_eid) -> max = (max score, min eid)
#define NEPT 9   // 9 * 1024 = 9216 = GSEG
__global__ __launch_bounds__(1024) void k_match(const int* __restrict__ gcnt,
    const int* __restrict__ bsrc, const int* __restrict__ bdst, const int* __restrict__ bem,
    const float* __restrict__ sc, const int* __restrict__ beid,
    int* __restrict__ cluster, float* __restrict__ nscore, int* __restrict__ partner, int* __restrict__ valid){
  int g = blockIdx.x;
  __shared__ unsigned long long best[PERG];   // 4 KB
  __shared__ unsigned char marked[PERG];
  __shared__ int flag;
  int t = threadIdx.x;
  for (int i=t;i<PERG;i+=1024) marked[i] = valid[g*PERG+i] ? 0 : 1;
  int nE = min(gcnt[g], GSEG);
  int base = g*GSEG;

  unsigned long long priR[NEPT];
  unsigned pkR[NEPT];
  unsigned live = 0u;
#pragma unroll
  for (int j=0;j<NEPT;j++){
    int k = t + j*1024;
    priR[j]=0ull; pkR[j]=0u;
    if (k < nE && bem[base+k]){
      int s = bsrc[base+k], d = bdst[base+k];
      pkR[j] = (unsigned)(((s&511)<<9) | (d&511));
      priR[j] = ((unsigned long long)__float_as_uint(sc[base+k]) << 18)
              | (unsigned long long)(0x3FFFFu - (unsigned)beid[base+k]);
      live |= (1u<<j);
    }
  }

  for (int round=0; round<512; ++round){
    for (int i=t;i<PERG;i+=1024) best[i]=0ull;
    if (t==0) flag = 0;
    __syncthreads();
    int any = 0;
#pragma unroll
    for (int j=0;j<NEPT;j++){
      if (!(live & (1u<<j))) continue;
      unsigned pk = pkR[j]; int ls = pk>>9, ld = pk&511;
      if (marked[ls] | marked[ld]){ live &= ~(1u<<j); continue; }
      any = 1;
      atomicMax(&best[ls], priR[j]);
      if (ld != ls) atomicMax(&best[ld], priR[j]);
    }
    if (any) flag = 1;
    __syncthreads();
    if (!flag) break;
#pragma unroll
    for (int j=0;j<NEPT;j++){
      if (!(live & (1u<<j))) continue;
      unsigned pk = pkR[j]; int ls = pk>>9, ld = pk&511;
      unsigned long long p = priR[j];
      if (best[ls]==p && best[ld]==p){
        int gs = g*PERG+ls, gd = g*PERG+ld;
        int rep = min(gs,gd), oth = max(gs,gd);
        unsigned sb = (unsigned)(p >> 18);
        cluster[oth] = rep;
        nscore[rep]  = __uint_as_float(sb);
        if (gs != gd){ valid[oth] = 0; partner[rep] = oth; }
        marked[ls] = 1; marked[ld] = 1;
        live &= ~(1u<<j);
      }
    }
    __syncthreads();
  }
}

// ---------- pool: new_x = relu((y[i]+y[partner]) * score * valid) ----------
template<int FO>
__global__ __launch_bounds__(256) void k_newx(const float* __restrict__ y, const int* __restrict__ partner,
    const float* __restrict__ nscore, const int* __restrict__ valid, float* __restrict__ out){
  constexpr int Q = (FO+63)/64;
  int lane = threadIdx.x & 63;
  int nblk = (blockIdx.x & 7)*512 + (blockIdx.x >> 3);
  int i = nblk*4 + (threadIdx.x>>6);
  int v = valid[i];
  float ns = nscore[i];
  int p = partner[i];
  const float* yi = y + (size_t)i*FO;
  const float* yp = (p>=0) ? (y + (size_t)p*FO) : yi;
  float* oi = out + (size_t)i*FO;
#pragma unroll
  for (int q=0;q<Q;q++){
    int c = lane + q*64;
    if (c<FO){
      float val = yi[c];
      if (p>=0) val += yp[c];
      val *= ns;
      oi[c] = v ? fmaxf(val,0.f) : 0.f;
    }
  }
}

// ---------- pool: remap edges + dedupe via per-graph key table ----------
__global__ void k_remap1(int* __restrict__ bsrc, int* __restrict__ bdst, const int* __restrict__ bem,
                         const int* __restrict__ gcnt, const int* __restrict__ cluster, int* __restrict__ table){
  int g = blockIdx.x / GBLK; int k = (blockIdx.x % GBLK)*256 + threadIdx.x;
  if (k >= gcnt[g]) return;
  int e = g*GSEG + k;
  if (bem[e]){
    int ns = cluster[bsrc[e]], nd = cluster[bdst[e]];
    bsrc[e]=ns; bdst[e]=nd;
    table[((ns>>9)<<18) | ((ns&511)<<9) | (nd&511)] = 0x7FFFFFFF;
  }
}
__global__ void k_remap2(const int* __restrict__ bsrc, const int* __restrict__ bdst,
                         const int* __restrict__ bem, const int* __restrict__ gcnt, int* __restrict__ table){
  int g = blockIdx.x / GBLK; int k = (blockIdx.x % GBLK)*256 + threadIdx.x;
  if (k >= gcnt[g]) return;
  int e = g*GSEG + k;
  if (bem[e]){
    int ns=bsrc[e], nd=bdst[e];
    atomicMin(&table[((ns>>9)<<18) | ((ns&511)<<9) | (nd&511)], e);
  }
}
__global__ void k_remap3(const int* __restrict__ bsrc, const int* __restrict__ bdst,
                         int* __restrict__ bem, const int* __restrict__ gcnt, const int* __restrict__ table){
  int g = blockIdx.x / GBLK; int k = (blockIdx.x % GBLK)*256 + threadIdx.x;
  if (k >= gcnt[g]) return;
  int e = g*GSEG + k;
  if (bem[e]){
    int ns=bsrc[e], nd=bdst[e];
    if (table[((ns>>9)<<18) | ((ns&511)<<9) | (nd&511)] != e) bem[e]=0;
  }
}

// ---------- readout ----------
__global__ __launch_bounds__(256) void k_gmax(const float* __restrict__ x, const int* __restrict__ valid,
                                              float* __restrict__ gbuf){
  int g = blockIdx.x;
  __shared__ int lv[PERG];
  for (int i=threadIdx.x;i<PERG;i+=256) lv[i] = valid[g*PERG+i];
  __syncthreads();
  const float* base = x + (size_t)g*PERG*600;
  for (int c=threadIdx.x; c<600; c+=256){
    float m = -1e30f;
    for (int r=0;r<PERG;r++)
      if (lv[r]) m = fmaxf(m, base[(size_t)r*600+c]);
    gbuf[g*600+c] = m;
  }
}
__global__ __launch_bounds__(256) void k_head(const float* __restrict__ gbuf,
    const float* __restrict__ L1w, const float* __restrict__ L1b,
    const float* __restrict__ L2w, const float* __restrict__ L2b,
    const float* __restrict__ L3w, const float* __restrict__ L3b, float* __restrict__ out){
  int g = blockIdx.x, t = threadIdx.x;
  __shared__ float gg[600];
  __shared__ float z1[200];
  __shared__ float z2[20];
  __shared__ float z3[4];
  for (int c=t;c<600;c+=256) gg[c] = gbuf[g*600+c];
  __syncthreads();
  if (t<200){
    float s = L1b[t];
    for (int k=0;k<600;k++) s += gg[k]*L1w[k*200+t];
    z1[t] = fmaxf(s,0.f);
  }
  __syncthreads();
  if (t<20){
    float s = L2b[t];
    for (int k=0;k<200;k++) s += z1[k]*L2w[k*20+t];
    z2[t] = fmaxf(s,0.f);
  }
  __syncthreads();
  if (t<4){
    float s = L3b[t];
    for (int k=0;k<20;k++) s += z2[k]*L3w[k*4+t];
    z3[t] = fmaxf(s,0.f);
  }
  __syncthreads();
  if (t==0){
    float m = fmaxf(fmaxf(z3[0],z3[1]), fmaxf(z3[2],z3[3]));
    float e0=expf(z3[0]-m), e1=expf(z3[1]-m), e2=expf(z3[2]-m), e3=expf(z3[3]-m);
    float s = e0+e1+e2+e3;
    out[g*4+0]=e0/s; out[g*4+1]=e1/s; out[g*4+2]=e2/s; out[g*4+3]=e3/s;
  }
}

// ---------- host orchestration ----------
struct WsPtrs {
  float *A, *B;
  int *bsrc, *bdst, *bem, *beid;
  float *sc;
  int *elist;
  int *cnt, *rowp, *cursor;
  float *dinv, *selfco;
  int *hs;
  unsigned *mx;
  float *den, *aval, *bval;
  int *cluster; float *nscore; int *partner; int *valid;
  int *gcount;
  float *gbuf;
};

template<int FO>
static void run_layer(const WsPtrs& P, const float* xin, int K,
                      const float* Wm, const float* bias,
                      const float* Pw, const float* Pb,
                      float* hbuf, float* ybuf, hipStream_t stream){
  const int NG4 = NN/4;            // 4096 blocks, wave per node
  const int NB = NN/256;           // 64 blocks for node kernels

  // h = x @ W
  dim3 gmm((FO+127)/128, NN/128);
  k_mm<<<gmm,256,0,stream>>>(xin, Wm, hbuf, NN, K, FO);

  // degree + CSR by dst
  hipMemsetAsync(P.cnt, 0, (NN+1)*sizeof(int), stream);
  hipMemsetAsync(P.hs,  0, NN*sizeof(int), stream);
  k_count<<<EGRID,256,0,stream>>>(P.bsrc, P.bdst, P.bem, P.gcount, P.cnt, P.hs);
  k_scan<<<1,1024,0,stream>>>(P.cnt, P.rowp, P.cursor);
  k_fill<<<EGRID,256,0,stream>>>(P.bdst, P.bem, P.gcount, P.cursor, P.elist);
  k_nodeprep<<<NB,256,0,stream>>>(P.cnt, P.hs, P.dinv, P.selfco);

  // y = agg + selfco*h + b
  k_agg<FO><<<NG4,256,0,stream>>>(hbuf, P.rowp, P.elist, P.bsrc, P.dinv, P.selfco, bias, ybuf);

  // edge scores (softmax grouped by dst)
  k_ab<FO><<<NG4,256,0,stream>>>(ybuf, Pw, P.aval, P.bval);
  hipMemsetAsync(P.mx,  0, NN*sizeof(unsigned), stream);
  k_raw<<<EGRID,256,0,stream>>>(P.bsrc, P.bdst, P.bem, P.gcount, P.aval, P.bval, Pb, P.sc, P.mx);
  hipMemsetAsync(P.den, 0, NN*sizeof(float), stream);
  k_ex<<<EGRID,256,0,stream>>>(P.bdst, P.bem, P.gcount, P.sc, P.mx, P.den);
  k_score<<<EGRID,256,0,stream>>>(P.bdst, P.bem, P.gcount, P.sc, P.den);

  // matching (per-graph fixed segments, edges in registers)
  k_poolinit<<<NB,256,0,stream>>>(P.cluster, P.nscore, P.partner);
  k_match<<<NGR,1024,0,stream>>>(P.gcount, P.bsrc, P.bdst, P.bem, P.sc, P.beid,
                                 P.cluster, P.nscore, P.partner, P.valid);

  // pooled features (relu fused) -> hbuf
  k_newx<FO><<<NG4,256,0,stream>>>(ybuf, P.partner, P.nscore, P.valid, hbuf);

  // remap + dedupe (table lives in the now-dead ybuf)
  int* table = (int*)ybuf;
  k_remap1<<<EGRID,256,0,stream>>>(P.bsrc, P.bdst, P.bem, P.gcount, P.cluster, table);
  k_remap2<<<EGRID,256,0,stream>>>(P.bsrc, P.bdst, P.bem, P.gcount, table);
  k_remap3<<<EGRID,256,0,stream>>>(P.bsrc, P.bdst, P.bem, P.gcount, table);
}

extern "C" void kernel_launch(void* const* d_in, const int* in_sizes, int n_in,
                              void* d_out, int out_size, void* d_ws, size_t ws_size,
                              hipStream_t stream){
  const float* x0  = (const float*)d_in[0];
  const int*   ei  = (const int*)  d_in[1];
  const float* W1  = (const float*)d_in[3];  const float* b1  = (const float*)d_in[4];
  const float* W2  = (const float*)d_in[5];  const float* b2  = (const float*)d_in[6];
  const float* W3  = (const float*)d_in[7];  const float* b3  = (const float*)d_in[8];
  const float* P1w = (const float*)d_in[9];  const float* P1b = (const float*)d_in[10];
  const float* P2w = (const float*)d_in[11]; const float* P2b = (const float*)d_in[12];
  const float* P3w = (const float*)d_in[13]; const float* P3b = (const float*)d_in[14];
  const float* L1w = (const float*)d_in[15]; const float* L1b = (const float*)d_in[16];
  const float* L2w = (const float*)d_in[17]; const float* L2b = (const float*)d_in[18];
  const float* L3w = (const float*)d_in[19]; const float* L3b = (const float*)d_in[20];
  float* out = (float*)d_out;

  char* w = (char*)d_ws;
  size_t off = 0;
  auto alloc = [&](size_t bytes)->void*{
    void* p = w + off;
    off += bytes;
    off = (off + 255) & ~(size_t)255;
    return p;
  };
  WsPtrs P;
  P.A     = (float*)alloc((size_t)NN*600*4);      // ping
  P.B     = (float*)alloc((size_t)NN*600*4);      // pong (also dedupe table home)
  P.bsrc  = (int*)  alloc((size_t)NGR*GSEG*4);
  P.bdst  = (int*)  alloc((size_t)NGR*GSEG*4);
  P.bem   = (int*)  alloc((size_t)NGR*GSEG*4);
  P.beid  = (int*)  alloc((size_t)NGR*GSEG*4);
  P.sc    = (float*)alloc((size_t)NGR*GSEG*4);
  P.elist = (int*)  alloc((size_t)NE*4);
  P.cnt    = (int*)alloc((size_t)(NN+1)*4);
  P.rowp   = (int*)alloc((size_t)(NN+1)*4);
  P.cursor = (int*)alloc((size_t)(NN+1)*4);
  P.dinv   = (float*)alloc((size_t)NN*4);
  P.selfco = (float*)alloc((size_t)NN*4);
  P.hs     = (int*)  alloc((size_t)NN*4);
  P.mx     = (unsigned*)alloc((size_t)NN*4);
  P.den    = (float*)alloc((size_t)NN*4);
  P.aval   = (float*)alloc((size_t)NN*4);
  P.bval   = (float*)alloc((size_t)NN*4);
  P.cluster= (int*)  alloc((size_t)NN*4);
  P.nscore = (float*)alloc((size_t)NN*4);
  P.partner= (int*)  alloc((size_t)NN*4);
  P.valid  = (int*)  alloc((size_t)NN*4);
  P.gcount = (int*)  alloc((size_t)NGR*4);
  P.gbuf   = (float*)alloc((size_t)NGR*600*4);
  (void)ws_size; (void)in_sizes; (void)n_in; (void)out_size;

  // one-time init: bucket edges graph-major, init valid flags
  hipMemsetAsync(P.gcount, 0, NGR*sizeof(int), stream);
  k_bucket<<<NE/256,256,0,stream>>>(ei, P.gcount, P.bsrc, P.bdst, P.bem, P.beid);
  k_init_nodes<<<NN/256,256,0,stream>>>(P.valid);

  // layer 1: x0[16384,107] -> h A -> y B -> newx A (table in B)
  run_layer<200>(P, x0,  107, W1, b1, P1w, P1b, P.A, P.B, stream);
  // layer 2: x=A -> h B -> y A -> newx B (table in A)
  run_layer<400>(P, P.A, 200, W2, b2, P2w, P2b, P.B, P.A, stream);
  // layer 3: x=B -> h A -> y B -> newx A (table in B)
  run_layer<600>(P, P.B, 400, W3, b3, P3w, P3b, P.A, P.B, stream);

  // readout + MLP head + softmax
  k_gmax<<<NGR,256,0,stream>>>(P.A, P.valid, P.gbuf);
  k_head<<<NGR,256,0,stream>>>(P.gbuf, L1w, L1b, L2w, L2b, L3w, L3b, out);
}

// Round 5
// 1143.765 us; speedup vs baseline: 4.2032x; 1.1304x over previous
//
#include <hip/hip_runtime.h>

#define NN 16384
#define PERG 512
#define NGR 32
#define NE 262144
#define GSEG 9216            // per-graph edge segment capacity (max count ~8.5k)

// ---------- helpers ----------
__device__ __forceinline__ unsigned encf(float f){
  unsigned u = __float_as_uint(f);
  return (u & 0x80000000u) ? ~u : (u | 0x80000000u);
}
__device__ __forceinline__ float decf(unsigned e){
  unsigned u = (e & 0x80000000u) ? (e ^ 0x80000000u) : ~e;
  return __uint_as_float(u);
}

// ---------- one-time: pad copies for K%16==0 GEMMs ----------
__global__ void k_padx(const float* __restrict__ x, float* __restrict__ xp){
  int i = blockIdx.x*256 + threadIdx.x;          // over NN*112
  if (i < NN*112){ int r = i/112, c = i-r*112; xp[i] = (c<107) ? x[r*107+c] : 0.f; }
}
__global__ void k_padw(const float* __restrict__ Wsrc, float* __restrict__ Wdst,
                       int Ksrc, int Kdst, int N){
  int i = blockIdx.x*256 + threadIdx.x;
  if (i < Kdst*N){ int r = i/N, c = i-r*N; Wdst[i] = (r<Ksrc) ? Wsrc[r*N+c] : 0.f; }
}

// ---------- one-time bucketing: edges -> graph-major segments ----------
__global__ __launch_bounds__(256) void k_bucket(const int* __restrict__ ei, int* __restrict__ gcount,
    int* __restrict__ bsrc, int* __restrict__ bdst, int* __restrict__ bem, int* __restrict__ beid){
  __shared__ int cnt[NGR];
  __shared__ int base[NGR];
  int t = threadIdx.x;
  if (t < NGR) cnt[t] = 0;
  __syncthreads();
  int e = blockIdx.x*256 + t;
  int s=0,d=0,g=0,r=0;
  bool ok = (e < NE);
  if (ok){ s = ei[e]; d = ei[NE+e]; g = s >> 9; r = atomicAdd(&cnt[g],1); }
  __syncthreads();
  if (t < NGR) base[t] = atomicAdd(&gcount[t], cnt[t]);
  __syncthreads();
  if (ok){
    int pos = g*GSEG + base[g] + r;
    bsrc[pos]=s; bdst[pos]=d; bem[pos]=1; beid[pos]=e;
  }
}
__global__ void k_init_nodes(int* __restrict__ valid){
  int i = blockIdx.x*256 + threadIdx.x;
  if (i < NN) valid[i]=1;
}

// ---------- dense matmul C[M,N] = A[M,KP] @ W[KP,N], f32, KP%16==0 ----------
// 128x128 tile, BK=16, padded LDS (132-float rows), register-prefetch dbuf.
__global__ __launch_bounds__(256) void k_mm(const float* __restrict__ A, const float* __restrict__ W,
                                            float* __restrict__ C, int KP, int N){
  __shared__ float As[16][132];
  __shared__ float Ws[16][132];
  int col0 = blockIdx.x*128, row0 = blockIdx.y*128;
  int t = threadIdx.x;
  int tx = t & 15, ty = t >> 4;
  // A-load mapping: two float4 per thread, same row, k-quads
  int ar  = t >> 1;
  int akq0 = (t&1)*2, akq1 = (t&1)*2 + 1;
  // W-load mapping
  int wk0 = (2*t) >> 5, wn0 = (2*t) & 31;
  int wk1 = (2*t+1) >> 5, wn1 = (2*t+1) & 31;
  int wc0 = col0 + wn0*4, wc1 = col0 + wn1*4;

  float4 a0,a1,w0,w1;
  auto loadT = [&](int k0){
    a0 = *(const float4*)&A[(size_t)(row0+ar)*KP + k0 + akq0*4];
    a1 = *(const float4*)&A[(size_t)(row0+ar)*KP + k0 + akq1*4];
    const float* p0 = &W[(size_t)(k0+wk0)*N + wc0];
    const float* p1 = &W[(size_t)(k0+wk1)*N + wc1];
    if (wc0+3 < N) w0 = *(const float4*)p0;
    else { w0.x=(wc0<N)?p0[0]:0.f; w0.y=(wc0+1<N)?p0[1]:0.f; w0.z=(wc0+2<N)?p0[2]:0.f; w0.w=0.f; }
    if (wc1+3 < N) w1 = *(const float4*)p1;
    else { w1.x=(wc1<N)?p1[0]:0.f; w1.y=(wc1+1<N)?p1[1]:0.f; w1.z=(wc1+2<N)?p1[2]:0.f; w1.w=0.f; }
  };
  auto storeT = [&](){
    As[akq0*4+0][ar]=a0.x; As[akq0*4+1][ar]=a0.y; As[akq0*4+2][ar]=a0.z; As[akq0*4+3][ar]=a0.w;
    As[akq1*4+0][ar]=a1.x; As[akq1*4+1][ar]=a1.y; As[akq1*4+2][ar]=a1.z; As[akq1*4+3][ar]=a1.w;
    *(float4*)&Ws[wk0][wn0*4] = w0;
    *(float4*)&Ws[wk1][wn1*4] = w1;
  };

  float acc[8][8];
#pragma unroll
  for (int i=0;i<8;i++)
#pragma unroll
    for (int j=0;j<8;j++) acc[i][j]=0.f;

  auto compute = [&](){
#pragma unroll
    for (int kk=0;kk<16;kk++){
      float4 A0 = *(const float4*)&As[kk][ty*4];
      float4 A1 = *(const float4*)&As[kk][64+ty*4];
      float4 B0 = *(const float4*)&Ws[kk][tx*4];
      float4 B1 = *(const float4*)&Ws[kk][64+tx*4];
      float a[8] = {A0.x,A0.y,A0.z,A0.w,A1.x,A1.y,A1.z,A1.w};
      float b[8] = {B0.x,B0.y,B0.z,B0.w,B1.x,B1.y,B1.z,B1.w};
#pragma unroll
      for (int i=0;i<8;i++)
#pragma unroll
        for (int j=0;j<8;j++) acc[i][j] += a[i]*b[j];
    }
  };

  loadT(0);
  storeT();
  __syncthreads();
  for (int k0=16; k0<KP; k0+=16){
    loadT(k0);          // prefetch next tile into regs
    compute();          // consume LDS
    __syncthreads();
    storeT();
    __syncthreads();
  }
  compute();

#pragma unroll
  for (int i=0;i<8;i++){
    int r = row0 + ((i<4)? ty*4+i : 64+ty*4+(i-4));
#pragma unroll
    for (int j=0;j<8;j++){
      int cc = col0 + ((j<4)? tx*4+j : 64+tx*4+(j-4));
      if (cc<N) C[(size_t)r*N+cc] = acc[i][j];
    }
  }
}

// ---------- per-graph CSR + node prep (fused, LDS) ----------
__global__ __launch_bounds__(1024) void k_prep(const int* __restrict__ bsrc, const int* __restrict__ bdst,
    const int* __restrict__ bem, const int* __restrict__ gcount,
    int* __restrict__ row_s, int* __restrict__ row_e, int* __restrict__ elist,
    float* __restrict__ dinv, float* __restrict__ selfco){
  int g = blockIdx.x, t = threadIdx.x;
  __shared__ int cnt_l[PERG];
  __shared__ int scn[PERG];
  __shared__ int cur[PERG];
  __shared__ unsigned char hs_l[PERG];
  if (t<PERG){ cnt_l[t]=0; hs_l[t]=0; }
  __syncthreads();
  int nE = min(gcount[g], GSEG); int base = g*GSEG;
  for (int k=t;k<nE;k+=1024){
    if (bem[base+k]){
      int d = bdst[base+k]&511;
      atomicAdd(&cnt_l[d],1);
      if (bsrc[base+k]==bdst[base+k]) hs_l[d]=1;
    }
  }
  __syncthreads();
  if (t<PERG) scn[t]=cnt_l[t];
  __syncthreads();
  for (int off=1; off<PERG; off<<=1){
    int v = (t<PERG && t>=off) ? scn[t-off] : 0;
    __syncthreads();
    if (t<PERG) scn[t]+=v;
    __syncthreads();
  }
  if (t<PERG){
    int excl = scn[t]-cnt_l[t];
    row_s[g*PERG+t] = base+excl;
    row_e[g*PERG+t] = base+scn[t];
    cur[t] = excl;
    float deg = (float)cnt_l[t] + (hs_l[t]?0.f:1.f);
    dinv[g*PERG+t]   = rsqrtf(deg);
    selfco[g*PERG+t] = hs_l[t]?0.f:(1.f/deg);
  }
  __syncthreads();
  for (int k=t;k<nE;k+=1024){
    if (bem[base+k]){
      int d = bdst[base+k]&511;
      elist[base + atomicAdd(&cur[d],1)] = base+k;
    }
  }
}

// ---------- GCN agg + bias + pool-score partials (fused; XCD-swizzled) ----------
template<int FO>
__global__ __launch_bounds__(256) void k_aggab(const float* __restrict__ h, const int* __restrict__ row_s,
    const int* __restrict__ row_e, const int* __restrict__ elist, const int* __restrict__ bsrc,
    const float* __restrict__ dinv, const float* __restrict__ selfco, const float* __restrict__ bias,
    const float* __restrict__ Pw, float* __restrict__ y, float* __restrict__ aval, float* __restrict__ bval){
  constexpr int Q = (FO+63)/64;
  int lane = threadIdx.x & 63;
  int nblk = (blockIdx.x & 7)*512 + (blockIdx.x >> 3);
  int i = nblk*4 + (threadIdx.x>>6);
  float acc[Q];
#pragma unroll
  for (int q=0;q<Q;q++) acc[q]=0.f;
  int s0 = row_s[i], s1 = row_e[i];
  float di = dinv[i];
  for (int p=s0; p<s1; p++){
    int e = elist[p]; int s = bsrc[e];
    float nr = di * dinv[s];
    const float* hrow = h + (size_t)s*FO;
#pragma unroll
    for (int q=0;q<Q;q++){ int c=lane+q*64; if (c<FO) acc[q] += nr*hrow[c]; }
  }
  float sc = selfco[i];
  const float* hi = h + (size_t)i*FO;
  float* yi = y + (size_t)i*FO;
  float sa=0.f, sb=0.f;
#pragma unroll
  for (int q=0;q<Q;q++){
    int c = lane+q*64;
    if (c<FO){
      float v = acc[q] + sc*hi[c] + bias[c];
      yi[c] = v;
      sa += v*Pw[c];
      sb += v*Pw[FO+c];
    }
  }
  for (int o=32;o;o>>=1){ sa += __shfl_xor(sa,o); sb += __shfl_xor(sb,o); }
  if (lane==0){ aval[i]=sa; bval[i]=sb; }
}

// ---------- pool: softmax + greedy match + remap + dedupe (one kernel, per graph) ----------
// priority = (score_bits << 18) | (0x3FFFF - orig_eid)  -> max = (max score, min eid)
#define NEPT 9   // 9 * 1024 = 9216 = GSEG
__global__ __launch_bounds__(1024) void k_pool(const int* __restrict__ gcount,
    int* __restrict__ bsrc, int* __restrict__ bdst, int* __restrict__ bem, const int* __restrict__ beid,
    const float* __restrict__ aval, const float* __restrict__ bval, const float* __restrict__ Pb,
    float* __restrict__ nscore, int* __restrict__ partner, int* __restrict__ valid, int* __restrict__ table){
  int g = blockIdx.x, t = threadIdx.x;
  __shared__ unsigned mx[PERG];
  __shared__ float den[PERG];
  __shared__ unsigned long long best[PERG];
  __shared__ unsigned char marked[PERG];
  __shared__ unsigned short clus[PERG];
  __shared__ int flag;
  int nE = min(gcount[g], GSEG), base = g*GSEG;
  if (t<PERG){
    mx[t]=0u; den[t]=0.f;
    marked[t] = valid[g*PERG+t] ? 0 : 1;
    clus[t] = (unsigned short)t;
    nscore[g*PERG+t] = 1.f;
    partner[g*PERG+t] = -1;
  }
  __syncthreads();

  int sL[NEPT], dL[NEPT];
  float rawv[NEPT];
  unsigned em = 0u;
#pragma unroll
  for (int j=0;j<NEPT;j++){
    sL[j]=0; dL[j]=0; rawv[j]=0.f;
    int k = t + j*1024;
    if (k < nE && bem[base+k]){
      sL[j] = bsrc[base+k]&511; dL[j] = bdst[base+k]&511;
      rawv[j] = aval[(g<<9)+sL[j]] + bval[(g<<9)+dL[j]] + Pb[0];
      em |= (1u<<j);
      atomicMax(&mx[dL[j]], encf(rawv[j]));
    }
  }
  __syncthreads();
  float exv[NEPT];
#pragma unroll
  for (int j=0;j<NEPT;j++){
    exv[j]=0.f;
    if (em & (1u<<j)){
      exv[j] = expf(rawv[j] - decf(mx[dL[j]]));
      atomicAdd(&den[dL[j]], exv[j]);
    }
  }
  __syncthreads();
  unsigned long long pri[NEPT];
#pragma unroll
  for (int j=0;j<NEPT;j++){
    pri[j]=0ull;
    if (em & (1u<<j)){
      int k = t + j*1024;
      float sc = exv[j]/fmaxf(den[dL[j]],1e-16f) + 0.1f;
      pri[j] = ((unsigned long long)__float_as_uint(sc) << 18)
             | (unsigned long long)(0x3FFFFu - (unsigned)beid[base+k]);
    }
  }

  // greedy matching (iterative lexicographic local-max)
  unsigned live = em;
  for (int round=0; round<512; ++round){
    if (t<PERG) best[t]=0ull;
    if (t==0) flag = 0;
    __syncthreads();
    int any = 0;
#pragma unroll
    for (int j=0;j<NEPT;j++){
      if (!(live & (1u<<j))) continue;
      int ls=sL[j], ld=dL[j];
      if (marked[ls] | marked[ld]){ live &= ~(1u<<j); continue; }
      any = 1;
      atomicMax(&best[ls], pri[j]);
      if (ld != ls) atomicMax(&best[ld], pri[j]);
    }
    if (any) flag = 1;
    __syncthreads();
    if (!flag) break;
#pragma unroll
    for (int j=0;j<NEPT;j++){
      if (!(live & (1u<<j))) continue;
      int ls=sL[j], ld=dL[j];
      unsigned long long p = pri[j];
      if (best[ls]==p && best[ld]==p){
        int repl = min(ls,ld), oth = max(ls,ld);
        clus[oth] = (unsigned short)repl;
        nscore[g*PERG+repl] = __uint_as_float((unsigned)(p>>18));
        if (ls != ld){ valid[g*PERG+oth] = 0; partner[g*PERG+repl] = g*PERG+oth; }
        marked[ls] = 1; marked[ld] = 1;
        live &= ~(1u<<j);
      }
    }
    __syncthreads();
  }
  __syncthreads();

  // remap + dedupe (graph-local key table in global scratch; 3 block-local passes)
#pragma unroll
  for (int j=0;j<NEPT;j++){
    if (em & (1u<<j)){
      int k = t + j*1024;
      int ns = clus[sL[j]], nd = clus[dL[j]];
      sL[j]=ns; dL[j]=nd;
      bsrc[base+k] = (g<<9)+ns; bdst[base+k] = (g<<9)+nd;
      table[(g<<18) | (ns<<9) | nd] = 0x7FFFFFFF;
    }
  }
  __syncthreads();
#pragma unroll
  for (int j=0;j<NEPT;j++){
    if (em & (1u<<j)){
      int k = t + j*1024;
      atomicMin(&table[(g<<18) | (sL[j]<<9) | dL[j]], base+k);
    }
  }
  __syncthreads();
#pragma unroll
  for (int j=0;j<NEPT;j++){
    if (em & (1u<<j)){
      int k = t + j*1024;
      if (table[(g<<18) | (sL[j]<<9) | dL[j]] != base+k) bem[base+k] = 0;
    }
  }
}

// ---------- pool: new_x = relu((y[i]+y[partner]) * score * valid), pad-zeroed ----------
template<int FO, int FOP>
__global__ __launch_bounds__(256) void k_newx(const float* __restrict__ y, const int* __restrict__ partner,
    const float* __restrict__ nscore, const int* __restrict__ valid, float* __restrict__ out){
  constexpr int Q = (FOP+63)/64;
  int lane = threadIdx.x & 63;
  int nblk = (blockIdx.x & 7)*512 + (blockIdx.x >> 3);
  int i = nblk*4 + (threadIdx.x>>6);
  int v = valid[i];
  float ns = nscore[i];
  int p = partner[i];
  const float* yi = y + (size_t)i*FO;
  const float* yp = (p>=0) ? (y + (size_t)p*FO) : yi;
  float* oi = out + (size_t)i*FOP;
#pragma unroll
  for (int q=0;q<Q;q++){
    int c = lane + q*64;
    if (c<FO){
      float val = yi[c];
      if (p>=0) val += yp[c];
      val *= ns;
      oi[c] = v ? fmaxf(val,0.f) : 0.f;
    } else if (c<FOP){
      oi[c] = 0.f;
    }
  }
}

// ---------- readout ----------
__global__ __launch_bounds__(256) void k_gmax(const float* __restrict__ x, const int* __restrict__ valid,
                                              float* __restrict__ gbuf){
  int g = blockIdx.x;
  __shared__ int lv[PERG];
  for (int i=threadIdx.x;i<PERG;i+=256) lv[i] = valid[g*PERG+i];
  __syncthreads();
  const float* base = x + (size_t)g*PERG*600;
  for (int c=threadIdx.x; c<600; c+=256){
    float m = -1e30f;
    for (int r=0;r<PERG;r++)
      if (lv[r]) m = fmaxf(m, base[(size_t)r*600+c]);
    gbuf[g*600+c] = m;
  }
}
__global__ __launch_bounds__(256) void k_head(const float* __restrict__ gbuf,
    const float* __restrict__ L1w, const float* __restrict__ L1b,
    const float* __restrict__ L2w, const float* __restrict__ L2b,
    const float* __restrict__ L3w, const float* __restrict__ L3b, float* __restrict__ out){
  int g = blockIdx.x, t = threadIdx.x;
  __shared__ float gg[600];
  __shared__ float z1[200];
  __shared__ float z2[20];
  __shared__ float z3[4];
  for (int c=t;c<600;c+=256) gg[c] = gbuf[g*600+c];
  __syncthreads();
  if (t<200){
    float s = L1b[t];
    for (int k=0;k<600;k++) s += gg[k]*L1w[k*200+t];
    z1[t] = fmaxf(s,0.f);
  }
  __syncthreads();
  if (t<20){
    float s = L2b[t];
    for (int k=0;k<200;k++) s += z1[k]*L2w[k*20+t];
    z2[t] = fmaxf(s,0.f);
  }
  __syncthreads();
  if (t<4){
    float s = L3b[t];
    for (int k=0;k<20;k++) s += z2[k]*L3w[k*4+t];
    z3[t] = fmaxf(s,0.f);
  }
  __syncthreads();
  if (t==0){
    float m = fmaxf(fmaxf(z3[0],z3[1]), fmaxf(z3[2],z3[3]));
    float e0=expf(z3[0]-m), e1=expf(z3[1]-m), e2=expf(z3[2]-m), e3=expf(z3[3]-m);
    float s = e0+e1+e2+e3;
    out[g*4+0]=e0/s; out[g*4+1]=e1/s; out[g*4+2]=e2/s; out[g*4+3]=e3/s;
  }
}

// ---------- host orchestration ----------
struct WsPtrs {
  float *A, *B, *x0p, *W1p, *W2p;
  int *bsrc, *bdst, *bem, *beid;
  int *elist, *row_s, *row_e;
  float *dinv, *selfco, *aval, *bval;
  float *nscore; int *partner; int *valid;
  int *gcount;
  float *gbuf;
};

extern "C" void kernel_launch(void* const* d_in, const int* in_sizes, int n_in,
                              void* d_out, int out_size, void* d_ws, size_t ws_size,
                              hipStream_t stream){
  const float* x0  = (const float*)d_in[0];
  const int*   ei  = (const int*)  d_in[1];
  const float* W1  = (const float*)d_in[3];  const float* b1  = (const float*)d_in[4];
  const float* W2  = (const float*)d_in[5];  const float* b2  = (const float*)d_in[6];
  const float* W3  = (const float*)d_in[7];  const float* b3  = (const float*)d_in[8];
  const float* P1w = (const float*)d_in[9];  const float* P1b = (const float*)d_in[10];
  const float* P2w = (const float*)d_in[11]; const float* P2b = (const float*)d_in[12];
  const float* P3w = (const float*)d_in[13]; const float* P3b = (const float*)d_in[14];
  const float* L1w = (const float*)d_in[15]; const float* L1b = (const float*)d_in[16];
  const float* L2w = (const float*)d_in[17]; const float* L2b = (const float*)d_in[18];
  const float* L3w = (const float*)d_in[19]; const float* L3b = (const float*)d_in[20];
  float* out = (float*)d_out;

  char* w = (char*)d_ws;
  size_t off = 0;
  auto alloc = [&](size_t bytes)->void*{
    void* p = w + off;
    off += bytes;
    off = (off + 255) & ~(size_t)255;
    return p;
  };
  WsPtrs P;
  P.A     = (float*)alloc((size_t)NN*600*4);   // ping (also hosts dedupe table when h dead)
  P.B     = (float*)alloc((size_t)NN*600*4);   // pong
  P.x0p   = (float*)alloc((size_t)NN*112*4);
  P.W1p   = (float*)alloc((size_t)112*200*4);
  P.W2p   = (float*)alloc((size_t)208*400*4);
  P.bsrc  = (int*)  alloc((size_t)NGR*GSEG*4);
  P.bdst  = (int*)  alloc((size_t)NGR*GSEG*4);
  P.bem   = (int*)  alloc((size_t)NGR*GSEG*4);
  P.beid  = (int*)  alloc((size_t)NGR*GSEG*4);
  P.elist = (int*)  alloc((size_t)NGR*GSEG*4);
  P.row_s = (int*)  alloc((size_t)NN*4);
  P.row_e = (int*)  alloc((size_t)NN*4);
  P.dinv   = (float*)alloc((size_t)NN*4);
  P.selfco = (float*)alloc((size_t)NN*4);
  P.aval   = (float*)alloc((size_t)NN*4);
  P.bval   = (float*)alloc((size_t)NN*4);
  P.nscore = (float*)alloc((size_t)NN*4);
  P.partner= (int*)  alloc((size_t)NN*4);
  P.valid  = (int*)  alloc((size_t)NN*4);
  P.gcount = (int*)  alloc((size_t)NGR*4);
  P.gbuf   = (float*)alloc((size_t)NGR*600*4);
  (void)ws_size; (void)in_sizes; (void)n_in; (void)out_size;

  const int NG4 = NN/4;

  // ---- one-time prep ----
  k_padx<<<(NN*112+255)/256,256,0,stream>>>(x0, P.x0p);
  k_padw<<<(112*200+255)/256,256,0,stream>>>(W1, P.W1p, 107, 112, 200);
  k_padw<<<(208*400+255)/256,256,0,stream>>>(W2, P.W2p, 200, 208, 400);
  hipMemsetAsync(P.gcount, 0, NGR*sizeof(int), stream);
  k_bucket<<<NE/256,256,0,stream>>>(ei, P.gcount, P.bsrc, P.bdst, P.bem, P.beid);
  k_init_nodes<<<NN/256,256,0,stream>>>(P.valid);

  // ---- layer 1: x0p[16384,112] -> h=A(200) -> y=B -> out1=A(stride 208) ----
  { dim3 gmm(2,128); k_mm<<<gmm,256,0,stream>>>(P.x0p, P.W1p, P.A, 112, 200); }
  k_prep<<<NGR,1024,0,stream>>>(P.bsrc,P.bdst,P.bem,P.gcount,P.row_s,P.row_e,P.elist,P.dinv,P.selfco);
  k_aggab<200><<<NG4,256,0,stream>>>(P.A,P.row_s,P.row_e,P.elist,P.bsrc,P.dinv,P.selfco,b1,P1w,P.B,P.aval,P.bval);
  k_pool<<<NGR,1024,0,stream>>>(P.gcount,P.bsrc,P.bdst,P.bem,P.beid,P.aval,P.bval,P1b,
                                P.nscore,P.partner,P.valid,(int*)P.A);
  k_newx<200,208><<<NG4,256,0,stream>>>(P.B,P.partner,P.nscore,P.valid,P.A);

  // ---- layer 2: A[16384,208] -> h=B(400) -> y=A -> out2=B(stride 400) ----
  { dim3 gmm(4,128); k_mm<<<gmm,256,0,stream>>>(P.A, P.W2p, P.B, 208, 400); }
  k_prep<<<NGR,1024,0,stream>>>(P.bsrc,P.bdst,P.bem,P.gcount,P.row_s,P.row_e,P.elist,P.dinv,P.selfco);
  k_aggab<400><<<NG4,256,0,stream>>>(P.B,P.row_s,P.row_e,P.elist,P.bsrc,P.dinv,P.selfco,b2,P2w,P.A,P.aval,P.bval);
  k_pool<<<NGR,1024,0,stream>>>(P.gcount,P.bsrc,P.bdst,P.bem,P.beid,P.aval,P.bval,P2b,
                                P.nscore,P.partner,P.valid,(int*)P.B);
  k_newx<400,400><<<NG4,256,0,stream>>>(P.A,P.partner,P.nscore,P.valid,P.B);

  // ---- layer 3: B[16384,400] -> h=A(600) -> y=B -> out3=A(stride 600) ----
  { dim3 gmm(5,128); k_mm<<<gmm,256,0,stream>>>(P.B, W3, P.A, 400, 600); }
  k_prep<<<NGR,1024,0,stream>>>(P.bsrc,P.bdst,P.bem,P.gcount,P.row_s,P.row_e,P.elist,P.dinv,P.selfco);
  k_aggab<600><<<NG4,256,0,stream>>>(P.A,P.row_s,P.row_e,P.elist,P.bsrc,P.dinv,P.selfco,b3,P3w,P.B,P.aval,P.bval);
  k_pool<<<NGR,1024,0,stream>>>(P.gcount,P.bsrc,P.bdst,P.bem,P.beid,P.aval,P.bval,P3b,
                                P.nscore,P.partner,P.valid,(int*)P.A);
  k_newx<600,600><<<NG4,256,0,stream>>>(P.B,P.partner,P.nscore,P.valid,P.A);

  // ---- readout + MLP head + softmax ----
  k_gmax<<<NGR,256,0,stream>>>(P.A, P.valid, P.gbuf);
  k_head<<<NGR,256,0,stream>>>(P.gbuf, L1w, L1b, L2w, L2b, L3w, L3b, out);
}

// Round 6
// 988.151 us; speedup vs baseline: 4.8651x; 1.1575x over previous
//
#include <hip/hip_runtime.h>

#define NN 16384
#define PERG 512
#define NGR 32
#define NE 262144
#define GSEG 9216            // per-graph edge segment capacity (max count ~8.5k)

// ---------- helpers ----------
__device__ __forceinline__ unsigned encf(float f){
  unsigned u = __float_as_uint(f);
  return (u & 0x80000000u) ? ~u : (u | 0x80000000u);
}
__device__ __forceinline__ float decf(unsigned e){
  unsigned u = (e & 0x80000000u) ? (e ^ 0x80000000u) : ~e;
  return __uint_as_float(u);
}

// ---------- one-time: pad copies for K%16==0 GEMMs ----------
__global__ void k_padx(const float* __restrict__ x, float* __restrict__ xp){
  int i = blockIdx.x*256 + threadIdx.x;          // over NN*112
  if (i < NN*112){ int r = i/112, c = i-r*112; xp[i] = (c<107) ? x[r*107+c] : 0.f; }
}
__global__ void k_padw(const float* __restrict__ Wsrc, float* __restrict__ Wdst,
                       int Ksrc, int Kdst, int N){
  int i = blockIdx.x*256 + threadIdx.x;
  if (i < Kdst*N){ int r = i/N, c = i-r*N; Wdst[i] = (r<Ksrc) ? Wsrc[r*N+c] : 0.f; }
}

// ---------- one-time bucketing: edges -> graph-major segments ----------
__global__ __launch_bounds__(256) void k_bucket(const int* __restrict__ ei, int* __restrict__ gcount,
    int* __restrict__ bsrc, int* __restrict__ bdst, int* __restrict__ bem, int* __restrict__ beid){
  __shared__ int cnt[NGR];
  __shared__ int base[NGR];
  int t = threadIdx.x;
  if (t < NGR) cnt[t] = 0;
  __syncthreads();
  int e = blockIdx.x*256 + t;
  int s=0,d=0,g=0,r=0;
  bool ok = (e < NE);
  if (ok){ s = ei[e]; d = ei[NE+e]; g = s >> 9; r = atomicAdd(&cnt[g],1); }
  __syncthreads();
  if (t < NGR) base[t] = atomicAdd(&gcount[t], cnt[t]);
  __syncthreads();
  if (ok){
    int pos = g*GSEG + base[g] + r;
    bsrc[pos]=s; bdst[pos]=d; bem[pos]=1; beid[pos]=e;
  }
}
__global__ void k_init_nodes(int* __restrict__ valid){
  int i = blockIdx.x*256 + threadIdx.x;
  if (i < NN) valid[i]=1;
}

// ---------- dense matmul C[M,N] = A[M,KP] @ W[KP,N], f32, KP%16==0 ----------
// 128x64 tile, BK=16, 256 threads, acc[8][4] (~80 VGPR -> high occupancy).
// Occupancy (not in-thread prefetch) hides latency: L3 grid = 1280 blocks ~5/CU.
__global__ __launch_bounds__(256) void k_mm(const float* __restrict__ A, const float* __restrict__ W,
                                            float* __restrict__ C, int KP, int N){
  __shared__ float As[16][132];   // A stored transposed: As[k][row], stride 132 -> 2-way (free) stores
  __shared__ float Ws[16][68];
  int col0 = blockIdx.x*64, row0 = blockIdx.y*128;
  int t = threadIdx.x;
  int tx = t & 15, ty = t >> 4;         // output map: rows ty*8..+7, cols tx*4..+3
  int ar = t >> 1;                      // A load: row, 2 float4 along k
  int ak = (t & 1) * 8;
  int wk = t >> 4;                      // W load: k-row, one float4 of cols
  int wn = (t & 15) * 4;
  int wc = col0 + wn;

  float acc[8][4];
#pragma unroll
  for (int i=0;i<8;i++)
#pragma unroll
    for (int j=0;j<4;j++) acc[i][j]=0.f;

  const float* Arow = A + (size_t)(row0+ar)*KP;

  for (int k0=0; k0<KP; k0+=16){
    float4 a0 = *(const float4*)&Arow[k0 + ak];
    float4 a1 = *(const float4*)&Arow[k0 + ak + 4];
    float4 w0;
    const float* wp = &W[(size_t)(k0+wk)*N + wc];
    if (wc+3 < N) w0 = *(const float4*)wp;
    else { w0.x=(wc<N)?wp[0]:0.f; w0.y=(wc+1<N)?wp[1]:0.f; w0.z=(wc+2<N)?wp[2]:0.f; w0.w=0.f; }
    __syncthreads();
    As[ak+0][ar]=a0.x; As[ak+1][ar]=a0.y; As[ak+2][ar]=a0.z; As[ak+3][ar]=a0.w;
    As[ak+4][ar]=a1.x; As[ak+5][ar]=a1.y; As[ak+6][ar]=a1.z; As[ak+7][ar]=a1.w;
    *(float4*)&Ws[wk][wn] = w0;
    __syncthreads();
#pragma unroll
    for (int kk=0;kk<16;kk++){
      float4 A0 = *(const float4*)&As[kk][ty*8];
      float4 A1 = *(const float4*)&As[kk][ty*8+4];
      float4 B0 = *(const float4*)&Ws[kk][tx*4];
      float a[8] = {A0.x,A0.y,A0.z,A0.w,A1.x,A1.y,A1.z,A1.w};
      float b[4] = {B0.x,B0.y,B0.z,B0.w};
#pragma unroll
      for (int i=0;i<8;i++)
#pragma unroll
        for (int j=0;j<4;j++) acc[i][j] += a[i]*b[j];
    }
  }

#pragma unroll
  for (int i=0;i<8;i++){
    int r = row0 + ty*8 + i;
    int cc = col0 + tx*4;
    if (cc+3 < N){
      float4 v = {acc[i][0],acc[i][1],acc[i][2],acc[i][3]};
      *(float4*)&C[(size_t)r*N+cc] = v;
    } else {
#pragma unroll
      for (int j=0;j<4;j++) if (cc+j<N) C[(size_t)r*N+cc+j] = acc[i][j];
    }
  }
}

// ---------- per-graph CSR + node prep (fused, LDS) ----------
__global__ __launch_bounds__(1024) void k_prep(const int* __restrict__ bsrc, const int* __restrict__ bdst,
    const int* __restrict__ bem, const int* __restrict__ gcount,
    int* __restrict__ row_s, int* __restrict__ row_e, int* __restrict__ elist,
    float* __restrict__ dinv, float* __restrict__ selfco){
  int g = blockIdx.x, t = threadIdx.x;
  __shared__ int cnt_l[PERG];
  __shared__ int scn[PERG];
  __shared__ int cur[PERG];
  __shared__ unsigned char hs_l[PERG];
  if (t<PERG){ cnt_l[t]=0; hs_l[t]=0; }
  __syncthreads();
  int nE = min(gcount[g], GSEG); int base = g*GSEG;
  for (int k=t;k<nE;k+=1024){
    if (bem[base+k]){
      int d = bdst[base+k]&511;
      atomicAdd(&cnt_l[d],1);
      if (bsrc[base+k]==bdst[base+k]) hs_l[d]=1;
    }
  }
  __syncthreads();
  if (t<PERG) scn[t]=cnt_l[t];
  __syncthreads();
  for (int off=1; off<PERG; off<<=1){
    int v = (t<PERG && t>=off) ? scn[t-off] : 0;
    __syncthreads();
    if (t<PERG) scn[t]+=v;
    __syncthreads();
  }
  if (t<PERG){
    int excl = scn[t]-cnt_l[t];
    row_s[g*PERG+t] = base+excl;
    row_e[g*PERG+t] = base+scn[t];
    cur[t] = excl;
    float deg = (float)cnt_l[t] + (hs_l[t]?0.f:1.f);
    dinv[g*PERG+t]   = rsqrtf(deg);
    selfco[g*PERG+t] = hs_l[t]?0.f:(1.f/deg);
  }
  __syncthreads();
  for (int k=t;k<nE;k+=1024){
    if (bem[base+k]){
      int d = bdst[base+k]&511;
      elist[base + atomicAdd(&cur[d],1)] = base+k;
    }
  }
}

// ---------- GCN agg + bias + pool-score partials (fused; XCD-swizzled) ----------
template<int FO>
__global__ __launch_bounds__(256) void k_aggab(const float* __restrict__ h, const int* __restrict__ row_s,
    const int* __restrict__ row_e, const int* __restrict__ elist, const int* __restrict__ bsrc,
    const float* __restrict__ dinv, const float* __restrict__ selfco, const float* __restrict__ bias,
    const float* __restrict__ Pw, float* __restrict__ y, float* __restrict__ aval, float* __restrict__ bval){
  constexpr int Q = (FO+63)/64;
  int lane = threadIdx.x & 63;
  int nblk = (blockIdx.x & 7)*512 + (blockIdx.x >> 3);
  int i = nblk*4 + (threadIdx.x>>6);
  float acc[Q];
#pragma unroll
  for (int q=0;q<Q;q++) acc[q]=0.f;
  int s0 = row_s[i], s1 = row_e[i];
  float di = dinv[i];
  for (int p=s0; p<s1; p++){
    int e = elist[p]; int s = bsrc[e];
    float nr = di * dinv[s];
    const float* hrow = h + (size_t)s*FO;
#pragma unroll
    for (int q=0;q<Q;q++){ int c=lane+q*64; if (c<FO) acc[q] += nr*hrow[c]; }
  }
  float sc = selfco[i];
  const float* hi = h + (size_t)i*FO;
  float* yi = y + (size_t)i*FO;
  float sa=0.f, sb=0.f;
#pragma unroll
  for (int q=0;q<Q;q++){
    int c = lane+q*64;
    if (c<FO){
      float v = acc[q] + sc*hi[c] + bias[c];
      yi[c] = v;
      sa += v*Pw[c];
      sb += v*Pw[FO+c];
    }
  }
  for (int o=32;o;o>>=1){ sa += __shfl_xor(sa,o); sb += __shfl_xor(sb,o); }
  if (lane==0){ aval[i]=sa; bval[i]=sb; }
}

// ---------- pool: softmax + greedy match + remap + dedupe (one kernel, per graph) ----------
// priority = (score_bits << 18) | (0x3FFFF - orig_eid)  -> max = (max score, min eid)
#define NEPT 9   // 9 * 1024 = 9216 = GSEG
__global__ __launch_bounds__(1024) void k_pool(const int* __restrict__ gcount,
    int* __restrict__ bsrc, int* __restrict__ bdst, int* __restrict__ bem, const int* __restrict__ beid,
    const float* __restrict__ aval, const float* __restrict__ bval, const float* __restrict__ Pb,
    float* __restrict__ nscore, int* __restrict__ partner, int* __restrict__ valid, int* __restrict__ table){
  int g = blockIdx.x, t = threadIdx.x;
  __shared__ unsigned mx[PERG];
  __shared__ float den[PERG];
  __shared__ unsigned long long best[PERG];
  __shared__ unsigned char marked[PERG];
  __shared__ unsigned short clus[PERG];
  __shared__ int flag;
  int nE = min(gcount[g], GSEG), base = g*GSEG;
  if (t<PERG){
    mx[t]=0u; den[t]=0.f;
    marked[t] = valid[g*PERG+t] ? 0 : 1;
    clus[t] = (unsigned short)t;
    nscore[g*PERG+t] = 1.f;
    partner[g*PERG+t] = -1;
  }
  __syncthreads();

  int sL[NEPT], dL[NEPT];
  float rawv[NEPT];
  unsigned em = 0u;
#pragma unroll
  for (int j=0;j<NEPT;j++){
    sL[j]=0; dL[j]=0; rawv[j]=0.f;
    int k = t + j*1024;
    if (k < nE && bem[base+k]){
      sL[j] = bsrc[base+k]&511; dL[j] = bdst[base+k]&511;
      rawv[j] = aval[(g<<9)+sL[j]] + bval[(g<<9)+dL[j]] + Pb[0];
      em |= (1u<<j);
      atomicMax(&mx[dL[j]], encf(rawv[j]));
    }
  }
  __syncthreads();
  float exv[NEPT];
#pragma unroll
  for (int j=0;j<NEPT;j++){
    exv[j]=0.f;
    if (em & (1u<<j)){
      exv[j] = expf(rawv[j] - decf(mx[dL[j]]));
      atomicAdd(&den[dL[j]], exv[j]);
    }
  }
  __syncthreads();
  unsigned long long pri[NEPT];
#pragma unroll
  for (int j=0;j<NEPT;j++){
    pri[j]=0ull;
    if (em & (1u<<j)){
      int k = t + j*1024;
      float sc = exv[j]/fmaxf(den[dL[j]],1e-16f) + 0.1f;
      pri[j] = ((unsigned long long)__float_as_uint(sc) << 18)
             | (unsigned long long)(0x3FFFFu - (unsigned)beid[base+k]);
    }
  }

  // greedy matching (iterative lexicographic local-max)
  unsigned live = em;
  for (int round=0; round<512; ++round){
    if (t<PERG) best[t]=0ull;
    if (t==0) flag = 0;
    __syncthreads();
    int any = 0;
#pragma unroll
    for (int j=0;j<NEPT;j++){
      if (!(live & (1u<<j))) continue;
      int ls=sL[j], ld=dL[j];
      if (marked[ls] | marked[ld]){ live &= ~(1u<<j); continue; }
      any = 1;
      atomicMax(&best[ls], pri[j]);
      if (ld != ls) atomicMax(&best[ld], pri[j]);
    }
    if (any) flag = 1;
    __syncthreads();
    if (!flag) break;
#pragma unroll
    for (int j=0;j<NEPT;j++){
      if (!(live & (1u<<j))) continue;
      int ls=sL[j], ld=dL[j];
      unsigned long long p = pri[j];
      if (best[ls]==p && best[ld]==p){
        int repl = min(ls,ld), oth = max(ls,ld);
        clus[oth] = (unsigned short)repl;
        nscore[g*PERG+repl] = __uint_as_float((unsigned)(p>>18));
        if (ls != ld){ valid[g*PERG+oth] = 0; partner[g*PERG+repl] = g*PERG+oth; }
        marked[ls] = 1; marked[ld] = 1;
        live &= ~(1u<<j);
      }
    }
    __syncthreads();
  }
  __syncthreads();

  // remap + dedupe (graph-local key table in global scratch; 3 block-local passes)
#pragma unroll
  for (int j=0;j<NEPT;j++){
    if (em & (1u<<j)){
      int k = t + j*1024;
      int ns = clus[sL[j]], nd = clus[dL[j]];
      sL[j]=ns; dL[j]=nd;
      bsrc[base+k] = (g<<9)+ns; bdst[base+k] = (g<<9)+nd;
      table[(g<<18) | (ns<<9) | nd] = 0x7FFFFFFF;
    }
  }
  __syncthreads();
#pragma unroll
  for (int j=0;j<NEPT;j++){
    if (em & (1u<<j)){
      int k = t + j*1024;
      atomicMin(&table[(g<<18) | (sL[j]<<9) | dL[j]], base+k);
    }
  }
  __syncthreads();
#pragma unroll
  for (int j=0;j<NEPT;j++){
    if (em & (1u<<j)){
      int k = t + j*1024;
      if (table[(g<<18) | (sL[j]<<9) | dL[j]] != base+k) bem[base+k] = 0;
    }
  }
}

// ---------- pool: new_x = relu((y[i]+y[partner]) * score * valid), pad-zeroed ----------
template<int FO, int FOP>
__global__ __launch_bounds__(256) void k_newx(const float* __restrict__ y, const int* __restrict__ partner,
    const float* __restrict__ nscore, const int* __restrict__ valid, float* __restrict__ out){
  constexpr int Q = (FOP+63)/64;
  int lane = threadIdx.x & 63;
  int nblk = (blockIdx.x & 7)*512 + (blockIdx.x >> 3);
  int i = nblk*4 + (threadIdx.x>>6);
  int v = valid[i];
  float ns = nscore[i];
  int p = partner[i];
  const float* yi = y + (size_t)i*FO;
  const float* yp = (p>=0) ? (y + (size_t)p*FO) : yi;
  float* oi = out + (size_t)i*FOP;
#pragma unroll
  for (int q=0;q<Q;q++){
    int c = lane + q*64;
    if (c<FO){
      float val = yi[c];
      if (p>=0) val += yp[c];
      val *= ns;
      oi[c] = v ? fmaxf(val,0.f) : 0.f;
    } else if (c<FOP){
      oi[c] = 0.f;
    }
  }
}

// ---------- readout: stage 1, per-(graph, 64-row part) partial max ----------
__global__ __launch_bounds__(256) void k_gmax(const float* __restrict__ x, const int* __restrict__ valid,
                                              float* __restrict__ part){
  int g = blockIdx.x >> 3, rp = blockIdx.x & 7;
  __shared__ int lv[64];
  int r0 = rp*64;
  if (threadIdx.x < 64) lv[threadIdx.x] = valid[g*PERG + r0 + threadIdx.x];
  __syncthreads();
  const float* base = x + ((size_t)g*PERG + r0)*600;
  for (int c=threadIdx.x; c<600; c+=256){
    float m = -1e30f;
    for (int r=0;r<64;r++)
      if (lv[r]) m = fmaxf(m, base[(size_t)r*600+c]);
    part[(size_t)(g*8+rp)*600 + c] = m;
  }
}
__global__ __launch_bounds__(256) void k_head(const float* __restrict__ part,
    const float* __restrict__ L1w, const float* __restrict__ L1b,
    const float* __restrict__ L2w, const float* __restrict__ L2b,
    const float* __restrict__ L3w, const float* __restrict__ L3b, float* __restrict__ out){
  int g = blockIdx.x, t = threadIdx.x;
  __shared__ float gg[600];
  __shared__ float z1[200];
  __shared__ float z2[20];
  __shared__ float z3[4];
  for (int c=t;c<600;c+=256){
    float m = -1e30f;
#pragma unroll
    for (int rp=0;rp<8;rp++) m = fmaxf(m, part[(size_t)(g*8+rp)*600 + c]);
    gg[c] = m;
  }
  __syncthreads();
  if (t<200){
    float s = L1b[t];
#pragma unroll 4
    for (int k=0;k<600;k++) s += gg[k]*L1w[k*200+t];
    z1[t] = fmaxf(s,0.f);
  }
  __syncthreads();
  if (t<20){
    float s = L2b[t];
#pragma unroll 4
    for (int k=0;k<200;k++) s += z1[k]*L2w[k*20+t];
    z2[t] = fmaxf(s,0.f);
  }
  __syncthreads();
  if (t<4){
    float s = L3b[t];
    for (int k=0;k<20;k++) s += z2[k]*L3w[k*4+t];
    z3[t] = fmaxf(s,0.f);
  }
  __syncthreads();
  if (t==0){
    float m = fmaxf(fmaxf(z3[0],z3[1]), fmaxf(z3[2],z3[3]));
    float e0=expf(z3[0]-m), e1=expf(z3[1]-m), e2=expf(z3[2]-m), e3=expf(z3[3]-m);
    float s = e0+e1+e2+e3;
    out[g*4+0]=e0/s; out[g*4+1]=e1/s; out[g*4+2]=e2/s; out[g*4+3]=e3/s;
  }
}

// ---------- host orchestration ----------
struct WsPtrs {
  float *A, *B, *x0p, *W1p, *W2p;
  int *bsrc, *bdst, *bem, *beid;
  int *elist, *row_s, *row_e;
  float *dinv, *selfco, *aval, *bval;
  float *nscore; int *partner; int *valid;
  int *gcount;
  float *gbuf;
};

extern "C" void kernel_launch(void* const* d_in, const int* in_sizes, int n_in,
                              void* d_out, int out_size, void* d_ws, size_t ws_size,
                              hipStream_t stream){
  const float* x0  = (const float*)d_in[0];
  const int*   ei  = (const int*)  d_in[1];
  const float* W1  = (const float*)d_in[3];  const float* b1  = (const float*)d_in[4];
  const float* W2  = (const float*)d_in[5];  const float* b2  = (const float*)d_in[6];
  const float* W3  = (const float*)d_in[7];  const float* b3  = (const float*)d_in[8];
  const float* P1w = (const float*)d_in[9];  const float* P1b = (const float*)d_in[10];
  const float* P2w = (const float*)d_in[11]; const float* P2b = (const float*)d_in[12];
  const float* P3w = (const float*)d_in[13]; const float* P3b = (const float*)d_in[14];
  const float* L1w = (const float*)d_in[15]; const float* L1b = (const float*)d_in[16];
  const float* L2w = (const float*)d_in[17]; const float* L2b = (const float*)d_in[18];
  const float* L3w = (const float*)d_in[19]; const float* L3b = (const float*)d_in[20];
  float* out = (float*)d_out;

  char* w = (char*)d_ws;
  size_t off = 0;
  auto alloc = [&](size_t bytes)->void*{
    void* p = w + off;
    off += bytes;
    off = (off + 255) & ~(size_t)255;
    return p;
  };
  WsPtrs P;
  P.A     = (float*)alloc((size_t)NN*600*4);   // ping (also hosts dedupe table when h dead)
  P.B     = (float*)alloc((size_t)NN*600*4);   // pong
  P.x0p   = (float*)alloc((size_t)NN*112*4);
  P.W1p   = (float*)alloc((size_t)112*200*4);
  P.W2p   = (float*)alloc((size_t)208*400*4);
  P.bsrc  = (int*)  alloc((size_t)NGR*GSEG*4);
  P.bdst  = (int*)  alloc((size_t)NGR*GSEG*4);
  P.bem   = (int*)  alloc((size_t)NGR*GSEG*4);
  P.beid  = (int*)  alloc((size_t)NGR*GSEG*4);
  P.elist = (int*)  alloc((size_t)NGR*GSEG*4);
  P.row_s = (int*)  alloc((size_t)NN*4);
  P.row_e = (int*)  alloc((size_t)NN*4);
  P.dinv   = (float*)alloc((size_t)NN*4);
  P.selfco = (float*)alloc((size_t)NN*4);
  P.aval   = (float*)alloc((size_t)NN*4);
  P.bval   = (float*)alloc((size_t)NN*4);
  P.nscore = (float*)alloc((size_t)NN*4);
  P.partner= (int*)  alloc((size_t)NN*4);
  P.valid  = (int*)  alloc((size_t)NN*4);
  P.gcount = (int*)  alloc((size_t)NGR*4);
  P.gbuf   = (float*)alloc((size_t)NGR*8*600*4);
  (void)ws_size; (void)in_sizes; (void)n_in; (void)out_size;

  const int NG4 = NN/4;

  // ---- one-time prep ----
  k_padx<<<(NN*112+255)/256,256,0,stream>>>(x0, P.x0p);
  k_padw<<<(112*200+255)/256,256,0,stream>>>(W1, P.W1p, 107, 112, 200);
  k_padw<<<(208*400+255)/256,256,0,stream>>>(W2, P.W2p, 200, 208, 400);
  hipMemsetAsync(P.gcount, 0, NGR*sizeof(int), stream);
  k_bucket<<<NE/256,256,0,stream>>>(ei, P.gcount, P.bsrc, P.bdst, P.bem, P.beid);
  k_init_nodes<<<NN/256,256,0,stream>>>(P.valid);

  // ---- layer 1: x0p[16384,112] -> h=A(200) -> y=B -> out1=A(stride 208) ----
  { dim3 gmm(4,128); k_mm<<<gmm,256,0,stream>>>(P.x0p, P.W1p, P.A, 112, 200); }
  k_prep<<<NGR,1024,0,stream>>>(P.bsrc,P.bdst,P.bem,P.gcount,P.row_s,P.row_e,P.elist,P.dinv,P.selfco);
  k_aggab<200><<<NG4,256,0,stream>>>(P.A,P.row_s,P.row_e,P.elist,P.bsrc,P.dinv,P.selfco,b1,P1w,P.B,P.aval,P.bval);
  k_pool<<<NGR,1024,0,stream>>>(P.gcount,P.bsrc,P.bdst,P.bem,P.beid,P.aval,P.bval,P1b,
                                P.nscore,P.partner,P.valid,(int*)P.A);
  k_newx<200,208><<<NG4,256,0,stream>>>(P.B,P.partner,P.nscore,P.valid,P.A);

  // ---- layer 2: A[16384,208] -> h=B(400) -> y=A -> out2=B(stride 400) ----
  { dim3 gmm(7,128); k_mm<<<gmm,256,0,stream>>>(P.A, P.W2p, P.B, 208, 400); }
  k_prep<<<NGR,1024,0,stream>>>(P.bsrc,P.bdst,P.bem,P.gcount,P.row_s,P.row_e,P.elist,P.dinv,P.selfco);
  k_aggab<400><<<NG4,256,0,stream>>>(P.B,P.row_s,P.row_e,P.elist,P.bsrc,P.dinv,P.selfco,b2,P2w,P.A,P.aval,P.bval);
  k_pool<<<NGR,1024,0,stream>>>(P.gcount,P.bsrc,P.bdst,P.bem,P.beid,P.aval,P.bval,P2b,
                                P.nscore,P.partner,P.valid,(int*)P.B);
  k_newx<400,400><<<NG4,256,0,stream>>>(P.A,P.partner,P.nscore,P.valid,P.B);

  // ---- layer 3: B[16384,400] -> h=A(600) -> y=B -> out3=A(stride 600) ----
  { dim3 gmm(10,128); k_mm<<<gmm,256,0,stream>>>(P.B, W3, P.A, 400, 600); }
  k_prep<<<NGR,1024,0,stream>>>(P.bsrc,P.bdst,P.bem,P.gcount,P.row_s,P.row_e,P.elist,P.dinv,P.selfco);
  k_aggab<600><<<NG4,256,0,stream>>>(P.A,P.row_s,P.row_e,P.elist,P.bsrc,P.dinv,P.selfco,b3,P3w,P.B,P.aval,P.bval);
  k_pool<<<NGR,1024,0,stream>>>(P.gcount,P.bsrc,P.bdst,P.bem,P.beid,P.aval,P.bval,P3b,
                                P.nscore,P.partner,P.valid,(int*)P.A);
  k_newx<600,600><<<NG4,256,0,stream>>>(P.B,P.partner,P.nscore,P.valid,P.A);

  // ---- readout + MLP head + softmax ----
  k_gmax<<<NGR*8,256,0,stream>>>(P.A, P.valid, P.gbuf);
  k_head<<<NGR,256,0,stream>>>(P.gbuf, L1w, L1b, L2w, L2b, L3w, L3b, out);
}